// Round 17
// baseline (929.121 us; speedup 1.0000x reference)
//
#include <hip/hip_runtime.h>
#include <math.h>

// SwinBlock on MI355X. Workspace (311.8 MB):
//   W(3.54MB bf16 B^T weights) | XW(77.07MB) | QKV(231.2MB natural [row][1152])
// Aliases: AO=XW, XN2=QKV(first 77MB), H1buf=QKV+38535168. XO lives in d_out.
// R16: 893us best (gemmP QKV/FC1 + gemmS proj/FC2).
// R17: NB 3->2 buffers at SANE launch bounds (the R8 experiment that was
//   sabotaged by lb(512,6) spill). gemmP: 48KB -> 3 blocks/CU = 6 waves/SIMD;
//   gemmS: 32KB -> 5 blocks/CU. Counted-vmcnt two-barrier schedule:
//   vmcnt(3)->barrier->ds_read+MFMA->barrier->stage(b,t+2) into just-read buf.
//   Tests the next TLP rung (ladder: 1->11%, 2-3->18%, 4->25%).

typedef float f32x4 __attribute__((ext_vector_type(4)));
typedef float f32x2 __attribute__((ext_vector_type(2)));
typedef __bf16 bf16x8 __attribute__((ext_vector_type(8)));
typedef short s16x8 __attribute__((ext_vector_type(8)));
typedef unsigned short u16x2 __attribute__((ext_vector_type(2)));

#define DEV static __device__ __forceinline__

DEV unsigned short f2bf(float f) {
  unsigned int u = __builtin_bit_cast(unsigned int, f);
  u += 0x7fffu + ((u >> 16) & 1u);
  return (unsigned short)(u >> 16);
}
DEV float bf2f(unsigned short h) {
  unsigned int u = ((unsigned int)h) << 16;
  return __builtin_bit_cast(float, u);
}
DEV void load_lds16(const void* g, void* l) {
  __builtin_amdgcn_global_load_lds(
      (const __attribute__((address_space(1))) unsigned int*)g,
      (__attribute__((address_space(3))) unsigned int*)l, 16, 0, 0);
}

// windowed row r (= win*49 + t, shifted coords) -> natural row in x.
DEV int win_src_row(int row) {
  int win = row / 49, t = row - win * 49;
  int bimg = win >> 6, wrem = win & 63;
  int wy = wrem >> 3, wx = wrem & 7;
  int ti = t / 7, tj = t - ti * 7;
  int hh = wy * 7 + ti, ww = wx * 7 + tj;
  int sh = hh + 3; if (sh >= 56) sh -= 56;
  int sw = ww + 3; if (sw >= 56) sw -= 56;
  return bimg * 3136 + sh * 56 + sw;
}

// ---------------- weight cast + transpose: w[K][N] f32 -> wt[N][K] bf16 ----
__global__ void wt_kernel(const float* __restrict__ w, unsigned short* __restrict__ wt,
                          int Kd, int Nd) {
  int idx = blockIdx.x * 256 + threadIdx.x;
  if (idx >= Kd * Nd) return;
  int n = idx / Kd, k = idx - n * Kd;
  wt[idx] = f2bf(w[(size_t)k * Nd + n]);
}

// ---------------- LayerNorm (+ optional shifted-window gather), one wave/row
template <int GATHER>
__global__ __launch_bounds__(256) void ln_kernel(const float* __restrict__ x,
                                                 const float* __restrict__ g,
                                                 const float* __restrict__ bb,
                                                 unsigned short* __restrict__ out) {
  int row = blockIdx.x * 4 + (threadIdx.x >> 6);
  int lane = threadIdx.x & 63;
  int src = GATHER ? win_src_row(row) : row;
  const float* xr = x + (size_t)src * 384;
  f32x2 p0 = *(const f32x2*)(xr + lane * 2);
  f32x2 p1 = *(const f32x2*)(xr + 128 + lane * 2);
  f32x2 p2 = *(const f32x2*)(xr + 256 + lane * 2);
  float s = p0.x + p0.y + p1.x + p1.y + p2.x + p2.y;
  float s2 = p0.x * p0.x + p0.y * p0.y + p1.x * p1.x + p1.y * p1.y +
             p2.x * p2.x + p2.y * p2.y;
#pragma unroll
  for (int off = 32; off; off >>= 1) {
    s += __shfl_xor(s, off);
    s2 += __shfl_xor(s2, off);
  }
  float mu = s * (1.0f / 384.0f);
  float rs = rsqrtf(s2 * (1.0f / 384.0f) - mu * mu + 1e-5f);
  unsigned short* orow = out + (size_t)row * 384;
  int c = lane * 2;
  u16x2 o;
  o.x = f2bf((p0.x - mu) * rs * g[c] + bb[c]);
  o.y = f2bf((p0.y - mu) * rs * g[c + 1] + bb[c + 1]);
  *(u16x2*)(orow + c) = o;
  c += 128;
  o.x = f2bf((p1.x - mu) * rs * g[c] + bb[c]);
  o.y = f2bf((p1.y - mu) * rs * g[c + 1] + bb[c + 1]);
  *(u16x2*)(orow + c) = o;
  c += 128;
  o.x = f2bf((p2.x - mu) * rs * g[c] + bb[c]);
  o.y = f2bf((p2.y - mu) * rs * g[c + 1] + bb[c + 1]);
  *(u16x2*)(orow + c) = o;
}

// ================= gemmP: 256x128 BK=32, NB=2, 3 blocks/CU ================
// 512 thr / 8 waves (4M x 2N), per-wave 64x64. 48KB LDS.
// Per K-tile: vmcnt(3|0) -> barrier -> 8 ds_read + 16 MFMA -> barrier ->
// stage(b, t+2) into the just-read buffer. Steady-state vmcnt never drains.
// Swizzle: 16B slot = chunk ^ ((row>>1)&3), pre-applied on global source.
// EPI 0: +bqkv bf16 stride 1152 | EPI 2: +bfc1 GELU bf16 stride 1536
template <int EPI>
__global__ __launch_bounds__(512, 4) void gemmP(const unsigned short* __restrict__ A,
                                                const unsigned short* __restrict__ BT,
                                                const float* __restrict__ bias, int Kd,
                                                int nTilesN, void* __restrict__ out0,
                                                const float* __restrict__ res) {
  constexpr int BM = 256, BN = 128, BK = 32;
  __shared__ __attribute__((aligned(16))) unsigned short As[2][BM * BK];
  __shared__ __attribute__((aligned(16))) unsigned short Bs[2][BN * BK];
  const int tid = threadIdx.x;
  const int wid = tid >> 6, lane = tid & 63;
  const int nwg = gridDim.x;
  const int xcd = blockIdx.x & 7, loc = blockIdx.x >> 3;
  const int q = nwg >> 3, rr = nwg & 7;
  const int swz = (xcd < rr ? xcd * (q + 1) : rr * (q + 1) + (xcd - rr) * q) + loc;
  const int bm = swz / nTilesN, bn = swz - bm * nTilesN;
  const int wr = wid >> 1, wc = wid & 1;
  f32x4 acc[4][4] = {};
  const int srow = tid >> 2;
  const int chunk = (tid & 3) ^ ((tid >> 3) & 3);
  const unsigned short* gA0 = A + (size_t)(bm * BM + srow) * Kd + chunk * 8;
  const unsigned short* gB0 = BT + (size_t)(bn * BN + srow) * Kd + chunk * 8;
  const size_t rowstep = (size_t)128 * Kd;

  auto STAGE = [&](int b, int t) {
    const int k0 = t << 5;
    unsigned short* lA = &As[b][tid * 8];
    load_lds16(gA0 + k0, lA);
    load_lds16(gA0 + k0 + rowstep, lA + 4096);
    load_lds16(gB0 + k0, &Bs[b][tid * 8]);
  };

  const int frow = lane & 15, g = lane >> 4;
  const int rslot = (g ^ ((frow >> 1) & 3)) << 3;
  const int aBase = (wr * 64 + frow) * BK + rslot;
  const int bBase = (wc * 64 + frow) * BK + rslot;

  const int nk = Kd >> 5;  // 12
  STAGE(0, 0);
  STAGE(1, 1);
  for (int t = 0; t < nk; ++t) {
    const int b = t & 1;
    __builtin_amdgcn_sched_barrier(0);
    if (t + 1 < nk) asm volatile("s_waitcnt vmcnt(3)");
    else asm volatile("s_waitcnt vmcnt(0)");
    __builtin_amdgcn_sched_barrier(0);
    __builtin_amdgcn_s_barrier();   // tile t visible to all waves
    __builtin_amdgcn_sched_barrier(0);
    const unsigned short* Ab = As[b];
    const unsigned short* Bb = Bs[b];
    bf16x8 af[4], bfr[4];
#pragma unroll
    for (int m = 0; m < 4; m++) af[m] = *(const bf16x8*)(Ab + aBase + m * 16 * BK);
#pragma unroll
    for (int n = 0; n < 4; n++) bfr[n] = *(const bf16x8*)(Bb + bBase + n * 16 * BK);
    asm volatile("s_waitcnt lgkmcnt(0)");
    __builtin_amdgcn_sched_barrier(0);
    __builtin_amdgcn_s_setprio(1);
#pragma unroll
    for (int m = 0; m < 4; m++)
#pragma unroll
      for (int n = 0; n < 4; n++)
        acc[m][n] = __builtin_amdgcn_mfma_f32_16x16x32_bf16(af[m], bfr[n], acc[m][n], 0, 0, 0);
    __builtin_amdgcn_s_setprio(0);
    __builtin_amdgcn_sched_barrier(0);
    __builtin_amdgcn_s_barrier();   // all waves done reading buf b
    __builtin_amdgcn_sched_barrier(0);
    if (t + 2 < nk) STAGE(b, t + 2);
  }
  const int rbase = bm * BM + wr * 64 + (g << 2);
  const int cbase = bn * BN + wc * 64 + frow;
#pragma unroll
  for (int m = 0; m < 4; m++) {
#pragma unroll
    for (int j = 0; j < 4; j++) {
      const int r = rbase + m * 16 + j;
      if constexpr (EPI == 0) {
        unsigned short* C = (unsigned short*)out0;
        size_t ro = (size_t)r * 1152;
#pragma unroll
        for (int n = 0; n < 4; n++) {
          int cc = cbase + n * 16;
          C[ro + cc] = f2bf(acc[m][n][j] + bias[cc]);
        }
      } else if constexpr (EPI == 2) {
        unsigned short* H1 = (unsigned short*)out0;
        size_t ro = (size_t)r * 1536;
#pragma unroll
        for (int n = 0; n < 4; n++) {
          int cc = cbase + n * 16;
          float u = acc[m][n][j] + bias[cc];
          H1[ro + cc] = f2bf(0.5f * u * (1.0f + erff(u * 0.70710678118654752f)));
        }
      }
    }
  }
}

// ================= gemmS: 128x128 BK=32, NB=2, 5 blocks/CU ================
// 256 thr / 4 waves (2M x 2N), per-wave 64x64. 32KB LDS. Same schedule.
// EPI 1: +bproj + x residual, inverse-window scatter, f32
// EPI 3: +bfc2 + in-place residual on f32 out (stride 384)
template <int EPI>
__global__ __launch_bounds__(256, 4) void gemmS(const unsigned short* __restrict__ A,
                                                const unsigned short* __restrict__ BT,
                                                const float* __restrict__ bias, int Kd,
                                                int nTilesN, void* __restrict__ out0,
                                                const float* __restrict__ res) {
  constexpr int BM = 128, BN = 128, BK = 32;
  __shared__ __attribute__((aligned(16))) unsigned short As[2][BM * BK];
  __shared__ __attribute__((aligned(16))) unsigned short Bs[2][BN * BK];
  const int tid = threadIdx.x;
  const int wid = tid >> 6, lane = tid & 63;
  const int nwg = gridDim.x;
  const int xcd = blockIdx.x & 7, loc = blockIdx.x >> 3;
  const int q = nwg >> 3, rr = nwg & 7;
  const int swz = (xcd < rr ? xcd * (q + 1) : rr * (q + 1) + (xcd - rr) * q) + loc;
  const int bm = swz / nTilesN, bn = swz - bm * nTilesN;
  const int wr = wid >> 1, wc = wid & 1;
  f32x4 acc[4][4] = {};
  const int srow = tid >> 2;
  const int chunk = (tid & 3) ^ ((tid >> 3) & 3);
  const unsigned short* gA0 = A + (size_t)(bm * BM + srow) * Kd + chunk * 8;
  const unsigned short* gB0 = BT + (size_t)(bn * BN + srow) * Kd + chunk * 8;
  const size_t rowstep = (size_t)64 * Kd;

  auto STAGE = [&](int b, int t) {
    const int k0 = t << 5;
    unsigned short* lA = &As[b][tid * 8];
    unsigned short* lB = &Bs[b][tid * 8];
    load_lds16(gA0 + k0, lA);
    load_lds16(gA0 + k0 + rowstep, lA + 2048);
    load_lds16(gB0 + k0, lB);
    load_lds16(gB0 + k0 + rowstep, lB + 2048);
  };

  const int frow = lane & 15, g = lane >> 4;
  const int rslot = (g ^ ((frow >> 1) & 3)) << 3;
  const int aBase = (wr * 64 + frow) * BK + rslot;
  const int bBase = (wc * 64 + frow) * BK + rslot;

  const int nk = Kd >> 5;  // 12 or 48
  STAGE(0, 0);
  STAGE(1, 1);
  for (int t = 0; t < nk; ++t) {
    const int b = t & 1;
    __builtin_amdgcn_sched_barrier(0);
    if (t + 1 < nk) asm volatile("s_waitcnt vmcnt(4)");
    else asm volatile("s_waitcnt vmcnt(0)");
    __builtin_amdgcn_sched_barrier(0);
    __builtin_amdgcn_s_barrier();
    __builtin_amdgcn_sched_barrier(0);
    const unsigned short* Ab = As[b];
    const unsigned short* Bb = Bs[b];
    bf16x8 af[4], bfr[4];
#pragma unroll
    for (int m = 0; m < 4; m++) af[m] = *(const bf16x8*)(Ab + aBase + m * 16 * BK);
#pragma unroll
    for (int n = 0; n < 4; n++) bfr[n] = *(const bf16x8*)(Bb + bBase + n * 16 * BK);
    asm volatile("s_waitcnt lgkmcnt(0)");
    __builtin_amdgcn_sched_barrier(0);
    __builtin_amdgcn_s_setprio(1);
#pragma unroll
    for (int m = 0; m < 4; m++)
#pragma unroll
      for (int n = 0; n < 4; n++)
        acc[m][n] = __builtin_amdgcn_mfma_f32_16x16x32_bf16(af[m], bfr[n], acc[m][n], 0, 0, 0);
    __builtin_amdgcn_s_setprio(0);
    __builtin_amdgcn_sched_barrier(0);
    __builtin_amdgcn_s_barrier();
    __builtin_amdgcn_sched_barrier(0);
    if (t + 2 < nk) STAGE(b, t + 2);
  }
  const int rbase = bm * BM + wr * 64 + (g << 2);
  const int cbase = bn * BN + wc * 64 + frow;
#pragma unroll
  for (int m = 0; m < 4; m++) {
#pragma unroll
    for (int j = 0; j < 4; j++) {
      const int r = rbase + m * 16 + j;
      if constexpr (EPI == 1) {
        float* XO = (float*)out0;
        size_t srowo = (size_t)win_src_row(r) * 384;
#pragma unroll
        for (int n = 0; n < 4; n++) {
          int cc = cbase + n * 16;
          XO[srowo + cc] = acc[m][n][j] + bias[cc] + res[srowo + cc];
        }
      } else {
        float* O = (float*)out0;
        size_t ro = (size_t)r * 384;
#pragma unroll
        for (int n = 0; n < 4; n++) {
          int cc = cbase + n * 16;
          O[ro + cc] = acc[m][n][j] + bias[cc] + res[ro + cc];
        }
      }
    }
  }
}

// ---------------- MFMA attention: 4 waves/block, one (win,head) per wave ----
__global__ __launch_bounds__(256) void attn_mfma(const unsigned short* __restrict__ QKV,
                                                 unsigned short* __restrict__ AO) {
  __shared__ __attribute__((aligned(16))) unsigned short L[4][7168];
  const int wid = threadIdx.x >> 6, lane = threadIdx.x & 63;
  const int blk = blockIdx.x * 4 + wid;
  const int win = blk / 12, head = blk - win * 12;
  unsigned short* Qs = L[wid];
  unsigned short* Ks = Qs + 2048;
  unsigned short* VT = Qs + 4096;
  unsigned short* Ps = Qs + 6144;
  const unsigned short* Qp = QKV + (size_t)win * 49 * 1152 + head * 32;
  for (int i = lane; i < 196; i += 64) {
    int row = i >> 2, c8 = (i & 3) << 3;
    const unsigned short* base = Qp + (size_t)row * 1152 + c8;
    *(s16x8*)(Qs + row * 32 + c8) = *(const s16x8*)(base);
    *(s16x8*)(Ks + row * 32 + c8) = *(const s16x8*)(base + 384);
    s16x8 vv = *(const s16x8*)(base + 768);
#pragma unroll
    for (int u = 0; u < 8; u++) VT[(c8 + u) * 64 + row] = (unsigned short)vv[u];
  }
  if (lane < 60) {
    s16x8 z = {};
    *(s16x8*)(Qs + 1568 + lane * 8) = z;
    *(s16x8*)(Ks + 1568 + lane * 8) = z;
  }
  for (int i = lane; i < 480; i += 64) {
    int d = i / 15, k = 49 + (i - d * 15);
    VT[d * 64 + k] = 0;
  }
  __syncthreads();

  const int g = lane >> 4, qi = lane & 15;
  const float scale = 0.17677669529663689f;
  bf16x8 kf[4];
#pragma unroll
  for (int mt = 0; mt < 4; mt++)
    kf[mt] = *(const bf16x8*)(Ks + (mt * 16 + qi) * 32 + g * 8);

  for (int nt = 0; nt < 4; nt++) {
    bf16x8 qf = *(const bf16x8*)(Qs + (nt * 16 + qi) * 32 + g * 8);
    f32x4 st[4];
#pragma unroll
    for (int mt = 0; mt < 4; mt++) {
      f32x4 zz = {};
      st[mt] = __builtin_amdgcn_mfma_f32_16x16x32_bf16(kf[mt], qf, zz, 0, 0, 0);
    }
    float m = -1e30f;
#pragma unroll
    for (int mt = 0; mt < 3; mt++)
#pragma unroll
      for (int j = 0; j < 4; j++) m = fmaxf(m, st[mt][j]);
    if (g == 0) m = fmaxf(m, st[3][0]);
    m = fmaxf(m, __shfl_xor(m, 16));
    m = fmaxf(m, __shfl_xor(m, 32));
    m *= scale;
    float p[4][4];
    float sum = 0.f;
#pragma unroll
    for (int mt = 0; mt < 4; mt++)
#pragma unroll
      for (int j = 0; j < 4; j++) {
        int k = mt * 16 + g * 4 + j;
        float e = (k < 49) ? __expf(st[mt][j] * scale - m) : 0.f;
        p[mt][j] = e;
        sum += e;
      }
    sum += __shfl_xor(sum, 16);
    sum += __shfl_xor(sum, 32);
    float inv = 1.0f / sum;
#pragma unroll
    for (int mt = 0; mt < 4; mt++)
#pragma unroll
      for (int j = 0; j < 4; j += 2) {
        unsigned int pk = (unsigned int)f2bf(p[mt][j]) |
                          ((unsigned int)f2bf(p[mt][j + 1]) << 16);
        *(unsigned int*)(Ps + qi * 64 + mt * 16 + g * 4 + j) = pk;
      }
    __syncthreads();
    f32x4 acc0 = {}, acc1 = {};
#pragma unroll
    for (int kt = 0; kt < 2; kt++) {
      bf16x8 pa = *(const bf16x8*)(Ps + qi * 64 + kt * 32 + g * 8);
      bf16x8 vb0 = *(const bf16x8*)(VT + qi * 64 + kt * 32 + g * 8);
      bf16x8 vb1 = *(const bf16x8*)(VT + (16 + qi) * 64 + kt * 32 + g * 8);
      acc0 = __builtin_amdgcn_mfma_f32_16x16x32_bf16(pa, vb0, acc0, 0, 0, 0);
      acc1 = __builtin_amdgcn_mfma_f32_16x16x32_bf16(pa, vb1, acc1, 0, 0, 0);
    }
#pragma unroll
    for (int jr = 0; jr < 4; jr++) {
      int q2 = g * 4 + jr;
      int qg = nt * 16 + q2;
      float iv = __shfl(inv, q2);
      if (qg < 49) {
        unsigned short* op = AO + ((size_t)win * 49 + qg) * 384 + head * 32 + qi;
        op[0] = f2bf(acc0[jr] * iv);
        op[16] = f2bf(acc1[jr] * iv);
      }
    }
    __syncthreads();
  }
}

extern "C" void kernel_launch(void* const* d_in, const int* in_sizes, int n_in,
                              void* d_out, int out_size, void* d_ws, size_t ws_size,
                              hipStream_t stream) {
  (void)in_sizes; (void)n_in; (void)out_size; (void)ws_size;
  const float* x = (const float*)d_in[0];
  const float* g1 = (const float*)d_in[3];
  const float* b1 = (const float*)d_in[4];
  const float* wqkv = (const float*)d_in[5];
  const float* bqkv = (const float*)d_in[6];
  const float* wproj = (const float*)d_in[7];
  const float* bproj = (const float*)d_in[8];
  const float* g2 = (const float*)d_in[9];
  const float* b2 = (const float*)d_in[10];
  const float* wfc1 = (const float*)d_in[11];
  const float* bfc1 = (const float*)d_in[12];
  const float* wfc2 = (const float*)d_in[13];
  const float* bfc2 = (const float*)d_in[14];

  char* ws = (char*)d_ws;
  unsigned short* wqkvT = (unsigned short*)ws;   // [1152][384]
  unsigned short* wprojT = wqkvT + 442368;       // [384][384]
  unsigned short* wfc1T = wprojT + 147456;       // [1536][384]
  unsigned short* wfc2T = wfc1T + 589824;        // [384][1536]
  unsigned short* XW = wfc2T + 589824;           // 100352x384 bf16
  unsigned short* QKV = XW + 38535168;           // 100352x1152 bf16
  unsigned short* AOb = XW;                      // attn out (XW dead)
  unsigned short* XN2 = QKV;                     // LN2 out (QKV dead, 77MB)
  unsigned short* H1buf = QKV + 38535168;        // 50176x1536 bf16
  float* XO = (float*)d_out;                     // residual stream in d_out
  float* out = (float*)d_out;

  wt_kernel<<<1728, 256, 0, stream>>>(wqkv, wqkvT, 384, 1152);
  wt_kernel<<<576, 256, 0, stream>>>(wproj, wprojT, 384, 384);
  wt_kernel<<<2304, 256, 0, stream>>>(wfc1, wfc1T, 384, 1536);
  wt_kernel<<<2304, 256, 0, stream>>>(wfc2, wfc2T, 1536, 384);

  ln_kernel<1><<<25088, 256, 0, stream>>>(x, g1, b1, XW);
  gemmP<0><<<392 * 9, 512, 0, stream>>>(XW, wqkvT, bqkv, 384, 9, QKV, nullptr);
  attn_mfma<<<6144, 256, 0, stream>>>(QKV, AOb);
  gemmS<1><<<784 * 3, 256, 0, stream>>>(AOb, wprojT, bproj, 384, 3, XO, x);
  ln_kernel<0><<<25088, 256, 0, stream>>>(XO, g2, b2, XN2);
  for (int ch = 0; ch < 2; ch++) {
    const unsigned short* a2 = XN2 + (size_t)ch * 50176 * 384;
    float* o2 = out + (size_t)ch * 50176 * 384;
    gemmP<2><<<196 * 12, 512, 0, stream>>>(a2, wfc1T, bfc1, 384, 12, H1buf, nullptr);
    gemmS<3><<<392 * 3, 256, 0, stream>>>(H1buf, wfc2T, bfc2, 1536, 3, o2, o2);
  }
}

// Round 18
// 875.159 us; speedup vs baseline: 1.0617x; 1.0617x over previous
//
#include <hip/hip_runtime.h>
#include <math.h>

// SwinBlock on MI355X. Workspace (311.8 MB):
//   W(3.54MB bf16 B^T weights) | XW(77.07MB) | QKV(231.2MB natural [row][1152])
// Aliases: AO=XW, XN2=QKV(first 77MB), H1buf=QKV+38535168. XO lives in d_out.
// R17 post-mortem: NB=2 regressed (893->929); occupancy did NOT rise (36%)
//   and prefetch got shallower. TLP exhausted at ~25% MfmaUtil. Revert to R16.
// R18: R16 + barrier-free attention: every LDS byte in attn_mfma is
//   wave-private (L[wid]), so all 9 __syncthreads() per block were pure
//   lockstep overhead; same-wave LDS ordering comes from lgkmcnt (compiler).

typedef float f32x4 __attribute__((ext_vector_type(4)));
typedef float f32x2 __attribute__((ext_vector_type(2)));
typedef __bf16 bf16x8 __attribute__((ext_vector_type(8)));
typedef short s16x8 __attribute__((ext_vector_type(8)));
typedef unsigned short u16x2 __attribute__((ext_vector_type(2)));

#define DEV static __device__ __forceinline__

DEV unsigned short f2bf(float f) {
  unsigned int u = __builtin_bit_cast(unsigned int, f);
  u += 0x7fffu + ((u >> 16) & 1u);
  return (unsigned short)(u >> 16);
}
DEV float bf2f(unsigned short h) {
  unsigned int u = ((unsigned int)h) << 16;
  return __builtin_bit_cast(float, u);
}
DEV void load_lds16(const void* g, void* l) {
  __builtin_amdgcn_global_load_lds(
      (const __attribute__((address_space(1))) unsigned int*)g,
      (__attribute__((address_space(3))) unsigned int*)l, 16, 0, 0);
}

// windowed row r (= win*49 + t, shifted coords) -> natural row in x.
DEV int win_src_row(int row) {
  int win = row / 49, t = row - win * 49;
  int bimg = win >> 6, wrem = win & 63;
  int wy = wrem >> 3, wx = wrem & 7;
  int ti = t / 7, tj = t - ti * 7;
  int hh = wy * 7 + ti, ww = wx * 7 + tj;
  int sh = hh + 3; if (sh >= 56) sh -= 56;
  int sw = ww + 3; if (sw >= 56) sw -= 56;
  return bimg * 3136 + sh * 56 + sw;
}

// ---------------- weight cast + transpose: w[K][N] f32 -> wt[N][K] bf16 ----
__global__ void wt_kernel(const float* __restrict__ w, unsigned short* __restrict__ wt,
                          int Kd, int Nd) {
  int idx = blockIdx.x * 256 + threadIdx.x;
  if (idx >= Kd * Nd) return;
  int n = idx / Kd, k = idx - n * Kd;
  wt[idx] = f2bf(w[(size_t)k * Nd + n]);
}

// ---------------- LayerNorm (+ optional shifted-window gather), one wave/row
template <int GATHER>
__global__ __launch_bounds__(256) void ln_kernel(const float* __restrict__ x,
                                                 const float* __restrict__ g,
                                                 const float* __restrict__ bb,
                                                 unsigned short* __restrict__ out) {
  int row = blockIdx.x * 4 + (threadIdx.x >> 6);
  int lane = threadIdx.x & 63;
  int src = GATHER ? win_src_row(row) : row;
  const float* xr = x + (size_t)src * 384;
  f32x2 p0 = *(const f32x2*)(xr + lane * 2);
  f32x2 p1 = *(const f32x2*)(xr + 128 + lane * 2);
  f32x2 p2 = *(const f32x2*)(xr + 256 + lane * 2);
  float s = p0.x + p0.y + p1.x + p1.y + p2.x + p2.y;
  float s2 = p0.x * p0.x + p0.y * p0.y + p1.x * p1.x + p1.y * p1.y +
             p2.x * p2.x + p2.y * p2.y;
#pragma unroll
  for (int off = 32; off; off >>= 1) {
    s += __shfl_xor(s, off);
    s2 += __shfl_xor(s2, off);
  }
  float mu = s * (1.0f / 384.0f);
  float rs = rsqrtf(s2 * (1.0f / 384.0f) - mu * mu + 1e-5f);
  unsigned short* orow = out + (size_t)row * 384;
  int c = lane * 2;
  u16x2 o;
  o.x = f2bf((p0.x - mu) * rs * g[c] + bb[c]);
  o.y = f2bf((p0.y - mu) * rs * g[c + 1] + bb[c + 1]);
  *(u16x2*)(orow + c) = o;
  c += 128;
  o.x = f2bf((p1.x - mu) * rs * g[c] + bb[c]);
  o.y = f2bf((p1.y - mu) * rs * g[c + 1] + bb[c + 1]);
  *(u16x2*)(orow + c) = o;
  c += 128;
  o.x = f2bf((p2.x - mu) * rs * g[c] + bb[c]);
  o.y = f2bf((p2.y - mu) * rs * g[c + 1] + bb[c + 1]);
  *(u16x2*)(orow + c) = o;
}

// ================= gemmP: 256x128 BK=32, NB=3 (R12/R16 proven) =============
// 512 thr / 8 waves (4M x 2N), per-wave 64x64. 72KB LDS -> 2 blocks/CU.
// Per K-tile 2 phases + end-of-tile vmcnt(3) handshake (never drains in
// steady state). Swizzle: 16B slot = chunk ^ ((row>>1)&3), both sides.
// EPI 0: +bqkv bf16 stride 1152 | EPI 2: +bfc1 GELU bf16 stride 1536
template <int EPI>
__global__ __launch_bounds__(512, 4) void gemmP(const unsigned short* __restrict__ A,
                                                const unsigned short* __restrict__ BT,
                                                const float* __restrict__ bias, int Kd,
                                                int nTilesN, void* __restrict__ out0,
                                                const float* __restrict__ res) {
  constexpr int BM = 256, BN = 128, BK = 32;
  __shared__ __attribute__((aligned(16))) unsigned short As[3][BM * BK];
  __shared__ __attribute__((aligned(16))) unsigned short Bs[3][BN * BK];
  const int tid = threadIdx.x;
  const int wid = tid >> 6, lane = tid & 63;
  const int nwg = gridDim.x;
  const int xcd = blockIdx.x & 7, loc = blockIdx.x >> 3;
  const int q = nwg >> 3, rr = nwg & 7;
  const int swz = (xcd < rr ? xcd * (q + 1) : rr * (q + 1) + (xcd - rr) * q) + loc;
  const int bm = swz / nTilesN, bn = swz - bm * nTilesN;
  const int wr = wid >> 1, wc = wid & 1;
  f32x4 acc[4][4] = {};
  const int srow = tid >> 2;
  const int chunk = (tid & 3) ^ ((tid >> 3) & 3);
  const unsigned short* gA0 = A + (size_t)(bm * BM + srow) * Kd + chunk * 8;
  const unsigned short* gB0 = BT + (size_t)(bn * BN + srow) * Kd + chunk * 8;
  const size_t rowstep = (size_t)128 * Kd;

  auto STAGE = [&](int b, int t) {
    const int k0 = t << 5;
    unsigned short* lA = &As[b][tid * 8];
    load_lds16(gA0 + k0, lA);
    load_lds16(gA0 + k0 + rowstep, lA + 4096);
    load_lds16(gB0 + k0, &Bs[b][tid * 8]);
  };

  const int frow = lane & 15, g = lane >> 4;
  const int rslot = (g ^ ((frow >> 1) & 3)) << 3;
  const int aBase = (wr * 64 + frow) * BK + rslot;
  const int bBase = (wc * 64 + frow) * BK + rslot;

  const int nk = Kd >> 5;
  {
    unsigned short* lA = &As[0][tid * 8];
    load_lds16(gA0, lA);
    load_lds16(gA0 + rowstep, lA + 4096);
    load_lds16(gB0, &Bs[0][tid * 8]);
    unsigned short* lA1 = &As[1][tid * 8];
    load_lds16(gA0 + 32, lA1);
    load_lds16(gA0 + 32 + rowstep, lA1 + 4096);
    load_lds16(gB0 + 32, &Bs[1][tid * 8]);
  }
  asm volatile("s_waitcnt vmcnt(3)");
  __builtin_amdgcn_sched_barrier(0);
  __builtin_amdgcn_s_barrier();
  int b = 0;
  for (int t = 0; t < nk; ++t) {
    const int bst = (b == 0) ? 2 : b - 1;
    const int k0n = (t + 2) << 5;
    const unsigned short* Ab = As[b];
    const unsigned short* Bb = Bs[b];
    __builtin_amdgcn_sched_barrier(0);
    bf16x8 af[4], bfr[2];
#pragma unroll
    for (int m = 0; m < 4; m++) af[m] = *(const bf16x8*)(Ab + aBase + m * 16 * BK);
#pragma unroll
    for (int n = 0; n < 2; n++) bfr[n] = *(const bf16x8*)(Bb + bBase + n * 16 * BK);
    if (t + 2 < nk) {
      unsigned short* lA = &As[bst][tid * 8];
      load_lds16(gA0 + k0n, lA);
      load_lds16(gA0 + k0n + rowstep, lA + 4096);
    }
    __builtin_amdgcn_sched_barrier(0);
    __builtin_amdgcn_s_barrier();
    asm volatile("s_waitcnt lgkmcnt(0)");
    __builtin_amdgcn_sched_barrier(0);
    __builtin_amdgcn_s_setprio(1);
#pragma unroll
    for (int m = 0; m < 4; m++)
#pragma unroll
      for (int n = 0; n < 2; n++)
        acc[m][n] = __builtin_amdgcn_mfma_f32_16x16x32_bf16(af[m], bfr[n], acc[m][n], 0, 0, 0);
    __builtin_amdgcn_s_setprio(0);
    __builtin_amdgcn_sched_barrier(0);
    __builtin_amdgcn_s_barrier();
    bf16x8 bfr2[2];
#pragma unroll
    for (int n = 0; n < 2; n++)
      bfr2[n] = *(const bf16x8*)(Bb + bBase + (n + 2) * 16 * BK);
    if (t + 2 < nk) load_lds16(gB0 + k0n, &Bs[bst][tid * 8]);
    __builtin_amdgcn_sched_barrier(0);
    __builtin_amdgcn_s_barrier();
    asm volatile("s_waitcnt lgkmcnt(0)");
    __builtin_amdgcn_sched_barrier(0);
    __builtin_amdgcn_s_setprio(1);
#pragma unroll
    for (int m = 0; m < 4; m++)
#pragma unroll
      for (int n = 0; n < 2; n++)
        acc[m][n + 2] = __builtin_amdgcn_mfma_f32_16x16x32_bf16(af[m], bfr2[n], acc[m][n + 2], 0, 0, 0);
    __builtin_amdgcn_s_setprio(0);
    __builtin_amdgcn_sched_barrier(0);
    if (t + 1 < nk) {
      if (t + 2 < nk) asm volatile("s_waitcnt vmcnt(3)");
      else asm volatile("s_waitcnt vmcnt(0)");
      __builtin_amdgcn_sched_barrier(0);
    }
    __builtin_amdgcn_s_barrier();
    b = (b == 2) ? 0 : b + 1;
  }
  const int rbase = bm * BM + wr * 64 + (g << 2);
  const int cbase = bn * BN + wc * 64 + frow;
#pragma unroll
  for (int m = 0; m < 4; m++) {
#pragma unroll
    for (int j = 0; j < 4; j++) {
      const int r = rbase + m * 16 + j;
      if constexpr (EPI == 0) {
        unsigned short* C = (unsigned short*)out0;
        size_t ro = (size_t)r * 1152;
#pragma unroll
        for (int n = 0; n < 4; n++) {
          int cc = cbase + n * 16;
          C[ro + cc] = f2bf(acc[m][n][j] + bias[cc]);
        }
      } else if constexpr (EPI == 2) {
        unsigned short* H1 = (unsigned short*)out0;
        size_t ro = (size_t)r * 1536;
#pragma unroll
        for (int n = 0; n < 4; n++) {
          int cc = cbase + n * 16;
          float u = acc[m][n][j] + bias[cc];
          H1[ro + cc] = f2bf(0.5f * u * (1.0f + erff(u * 0.70710678118654752f)));
        }
      }
    }
  }
}

// ================= gemmS: BM=128, NB=3, 48KB (R16 proven) ==================
// 256 thr / 4 waves (2M x 2N). EPI 1: proj+res inv-window f32;
// EPI 3: +bfc2 + in-place residual f32 (stride 384).
template <int EPI>
__global__ __launch_bounds__(256, 3) void gemmS(const unsigned short* __restrict__ A,
                                                const unsigned short* __restrict__ BT,
                                                const float* __restrict__ bias, int Kd,
                                                int nTilesN, void* __restrict__ out0,
                                                const float* __restrict__ res) {
  constexpr int BM = 128, BN = 128, BK = 32;
  __shared__ __attribute__((aligned(16))) unsigned short As[3][BM * BK];
  __shared__ __attribute__((aligned(16))) unsigned short Bs[3][BN * BK];
  const int tid = threadIdx.x;
  const int wid = tid >> 6, lane = tid & 63;
  const int nwg = gridDim.x;
  const int xcd = blockIdx.x & 7, loc = blockIdx.x >> 3;
  const int q = nwg >> 3, rr = nwg & 7;
  const int swz = (xcd < rr ? xcd * (q + 1) : rr * (q + 1) + (xcd - rr) * q) + loc;
  const int bm = swz / nTilesN, bn = swz - bm * nTilesN;
  const int wr = wid >> 1, wc = wid & 1;
  f32x4 acc[4][4] = {};
  const int srow = tid >> 2;
  const int chunk = (tid & 3) ^ ((tid >> 3) & 3);
  const unsigned short* gA0 = A + (size_t)(bm * BM + srow) * Kd + chunk * 8;
  const unsigned short* gB0 = BT + (size_t)(bn * BN + srow) * Kd + chunk * 8;
  const size_t rowstep = (size_t)64 * Kd;

  auto STAGE = [&](int b, int t) {
    const int k0 = t << 5;
    unsigned short* lA = &As[b][tid * 8];
    unsigned short* lB = &Bs[b][tid * 8];
    load_lds16(gA0 + k0, lA);
    load_lds16(gA0 + k0 + rowstep, lA + 2048);
    load_lds16(gB0 + k0, lB);
    load_lds16(gB0 + k0 + rowstep, lB + 2048);
  };

  const int frow = lane & 15, g = lane >> 4;
  const int rslot = (g ^ ((frow >> 1) & 3)) << 3;
  const int aBase = (wr * 64 + frow) * BK + rslot;
  const int bBase = (wc * 64 + frow) * BK + rslot;

  const int nk = Kd >> 5;  // 12 or 48
  STAGE(0, 0);
  STAGE(1, 1);
  asm volatile("s_waitcnt vmcnt(4)");
  __builtin_amdgcn_sched_barrier(0);
  __builtin_amdgcn_s_barrier();
  int b = 0;
  for (int t = 0; t < nk; ++t) {
    const int bst = (b == 0) ? 2 : b - 1;
    const unsigned short* Ab = As[b];
    const unsigned short* Bb = Bs[b];
    __builtin_amdgcn_sched_barrier(0);
    bf16x8 af[4], bfr[2];
#pragma unroll
    for (int m = 0; m < 4; m++) af[m] = *(const bf16x8*)(Ab + aBase + m * 16 * BK);
#pragma unroll
    for (int n = 0; n < 2; n++) bfr[n] = *(const bf16x8*)(Bb + bBase + n * 16 * BK);
    if (t + 2 < nk) {
      const int k0n = (t + 2) << 5;
      unsigned short* lA = &As[bst][tid * 8];
      load_lds16(gA0 + k0n, lA);
      load_lds16(gA0 + k0n + rowstep, lA + 2048);
    }
    __builtin_amdgcn_sched_barrier(0);
    __builtin_amdgcn_s_barrier();
    asm volatile("s_waitcnt lgkmcnt(0)");
    __builtin_amdgcn_sched_barrier(0);
    __builtin_amdgcn_s_setprio(1);
#pragma unroll
    for (int m = 0; m < 4; m++)
#pragma unroll
      for (int n = 0; n < 2; n++)
        acc[m][n] = __builtin_amdgcn_mfma_f32_16x16x32_bf16(af[m], bfr[n], acc[m][n], 0, 0, 0);
    __builtin_amdgcn_s_setprio(0);
    __builtin_amdgcn_sched_barrier(0);
    __builtin_amdgcn_s_barrier();
    bf16x8 bfr2[2];
#pragma unroll
    for (int n = 0; n < 2; n++)
      bfr2[n] = *(const bf16x8*)(Bb + bBase + (n + 2) * 16 * BK);
    if (t + 2 < nk) {
      const int k0n = (t + 2) << 5;
      unsigned short* lB = &Bs[bst][tid * 8];
      load_lds16(gB0 + k0n, lB);
      load_lds16(gB0 + k0n + rowstep, lB + 2048);
    }
    __builtin_amdgcn_sched_barrier(0);
    __builtin_amdgcn_s_barrier();
    asm volatile("s_waitcnt lgkmcnt(0)");
    __builtin_amdgcn_sched_barrier(0);
    __builtin_amdgcn_s_setprio(1);
#pragma unroll
    for (int m = 0; m < 4; m++)
#pragma unroll
      for (int n = 0; n < 2; n++)
        acc[m][n + 2] = __builtin_amdgcn_mfma_f32_16x16x32_bf16(af[m], bfr2[n], acc[m][n + 2], 0, 0, 0);
    __builtin_amdgcn_s_setprio(0);
    __builtin_amdgcn_sched_barrier(0);
    if (t + 1 < nk) {
      if (t + 2 < nk) asm volatile("s_waitcnt vmcnt(4)");
      else asm volatile("s_waitcnt vmcnt(0)");
      __builtin_amdgcn_sched_barrier(0);
    }
    __builtin_amdgcn_s_barrier();
    b = (b == 2) ? 0 : b + 1;
  }
  const int rbase = bm * BM + wr * 64 + (g << 2);
  const int cbase = bn * BN + wc * 64 + frow;
#pragma unroll
  for (int m = 0; m < 4; m++) {
#pragma unroll
    for (int j = 0; j < 4; j++) {
      const int r = rbase + m * 16 + j;
      if constexpr (EPI == 1) {
        float* XO = (float*)out0;
        size_t srowo = (size_t)win_src_row(r) * 384;
#pragma unroll
        for (int n = 0; n < 4; n++) {
          int cc = cbase + n * 16;
          XO[srowo + cc] = acc[m][n][j] + bias[cc] + res[srowo + cc];
        }
      } else {
        float* O = (float*)out0;
        size_t ro = (size_t)r * 384;
#pragma unroll
        for (int n = 0; n < 4; n++) {
          int cc = cbase + n * 16;
          O[ro + cc] = acc[m][n][j] + bias[cc] + res[ro + cc];
        }
      }
    }
  }
}

// ---------------- MFMA attention: 4 waves/block, one (win,head) per wave ----
// All LDS in L[wid] is WAVE-PRIVATE: no __syncthreads() needed anywhere —
// same-wave LDS write->read ordering is enforced by compiler lgkmcnt waits.
__global__ __launch_bounds__(256) void attn_mfma(const unsigned short* __restrict__ QKV,
                                                 unsigned short* __restrict__ AO) {
  __shared__ __attribute__((aligned(16))) unsigned short L[4][7168];
  const int wid = threadIdx.x >> 6, lane = threadIdx.x & 63;
  const int blk = blockIdx.x * 4 + wid;
  const int win = blk / 12, head = blk - win * 12;
  unsigned short* Qs = L[wid];
  unsigned short* Ks = Qs + 2048;
  unsigned short* VT = Qs + 4096;
  unsigned short* Ps = Qs + 6144;
  const unsigned short* Qp = QKV + (size_t)win * 49 * 1152 + head * 32;
  for (int i = lane; i < 196; i += 64) {
    int row = i >> 2, c8 = (i & 3) << 3;
    const unsigned short* base = Qp + (size_t)row * 1152 + c8;
    *(s16x8*)(Qs + row * 32 + c8) = *(const s16x8*)(base);
    *(s16x8*)(Ks + row * 32 + c8) = *(const s16x8*)(base + 384);
    s16x8 vv = *(const s16x8*)(base + 768);
#pragma unroll
    for (int u = 0; u < 8; u++) VT[(c8 + u) * 64 + row] = (unsigned short)vv[u];
  }
  if (lane < 60) {
    s16x8 z = {};
    *(s16x8*)(Qs + 1568 + lane * 8) = z;
    *(s16x8*)(Ks + 1568 + lane * 8) = z;
  }
  for (int i = lane; i < 480; i += 64) {
    int d = i / 15, k = 49 + (i - d * 15);
    VT[d * 64 + k] = 0;
  }

  const int g = lane >> 4, qi = lane & 15;
  const float scale = 0.17677669529663689f;
  bf16x8 kf[4];
#pragma unroll
  for (int mt = 0; mt < 4; mt++)
    kf[mt] = *(const bf16x8*)(Ks + (mt * 16 + qi) * 32 + g * 8);

  for (int nt = 0; nt < 4; nt++) {
    bf16x8 qf = *(const bf16x8*)(Qs + (nt * 16 + qi) * 32 + g * 8);
    f32x4 st[4];
#pragma unroll
    for (int mt = 0; mt < 4; mt++) {
      f32x4 zz = {};
      st[mt] = __builtin_amdgcn_mfma_f32_16x16x32_bf16(kf[mt], qf, zz, 0, 0, 0);
    }
    float m = -1e30f;
#pragma unroll
    for (int mt = 0; mt < 3; mt++)
#pragma unroll
      for (int j = 0; j < 4; j++) m = fmaxf(m, st[mt][j]);
    if (g == 0) m = fmaxf(m, st[3][0]);
    m = fmaxf(m, __shfl_xor(m, 16));
    m = fmaxf(m, __shfl_xor(m, 32));
    m *= scale;
    float p[4][4];
    float sum = 0.f;
#pragma unroll
    for (int mt = 0; mt < 4; mt++)
#pragma unroll
      for (int j = 0; j < 4; j++) {
        int k = mt * 16 + g * 4 + j;
        float e = (k < 49) ? __expf(st[mt][j] * scale - m) : 0.f;
        p[mt][j] = e;
        sum += e;
      }
    sum += __shfl_xor(sum, 16);
    sum += __shfl_xor(sum, 32);
    float inv = 1.0f / sum;
#pragma unroll
    for (int mt = 0; mt < 4; mt++)
#pragma unroll
      for (int j = 0; j < 4; j += 2) {
        unsigned int pk = (unsigned int)f2bf(p[mt][j]) |
                          ((unsigned int)f2bf(p[mt][j + 1]) << 16);
        *(unsigned int*)(Ps + qi * 64 + mt * 16 + g * 4 + j) = pk;
      }
    f32x4 acc0 = {}, acc1 = {};
#pragma unroll
    for (int kt = 0; kt < 2; kt++) {
      bf16x8 pa = *(const bf16x8*)(Ps + qi * 64 + kt * 32 + g * 8);
      bf16x8 vb0 = *(const bf16x8*)(VT + qi * 64 + kt * 32 + g * 8);
      bf16x8 vb1 = *(const bf16x8*)(VT + (16 + qi) * 64 + kt * 32 + g * 8);
      acc0 = __builtin_amdgcn_mfma_f32_16x16x32_bf16(pa, vb0, acc0, 0, 0, 0);
      acc1 = __builtin_amdgcn_mfma_f32_16x16x32_bf16(pa, vb1, acc1, 0, 0, 0);
    }
#pragma unroll
    for (int jr = 0; jr < 4; jr++) {
      int q2 = g * 4 + jr;
      int qg = nt * 16 + q2;
      float iv = __shfl(inv, q2);
      if (qg < 49) {
        unsigned short* op = AO + ((size_t)win * 49 + qg) * 384 + head * 32 + qi;
        op[0] = f2bf(acc0[jr] * iv);
        op[16] = f2bf(acc1[jr] * iv);
      }
    }
  }
}

extern "C" void kernel_launch(void* const* d_in, const int* in_sizes, int n_in,
                              void* d_out, int out_size, void* d_ws, size_t ws_size,
                              hipStream_t stream) {
  (void)in_sizes; (void)n_in; (void)out_size; (void)ws_size;
  const float* x = (const float*)d_in[0];
  const float* g1 = (const float*)d_in[3];
  const float* b1 = (const float*)d_in[4];
  const float* wqkv = (const float*)d_in[5];
  const float* bqkv = (const float*)d_in[6];
  const float* wproj = (const float*)d_in[7];
  const float* bproj = (const float*)d_in[8];
  const float* g2 = (const float*)d_in[9];
  const float* b2 = (const float*)d_in[10];
  const float* wfc1 = (const float*)d_in[11];
  const float* bfc1 = (const float*)d_in[12];
  const float* wfc2 = (const float*)d_in[13];
  const float* bfc2 = (const float*)d_in[14];

  char* ws = (char*)d_ws;
  unsigned short* wqkvT = (unsigned short*)ws;   // [1152][384]
  unsigned short* wprojT = wqkvT + 442368;       // [384][384]
  unsigned short* wfc1T = wprojT + 147456;       // [1536][384]
  unsigned short* wfc2T = wfc1T + 589824;        // [384][1536]
  unsigned short* XW = wfc2T + 589824;           // 100352x384 bf16
  unsigned short* QKV = XW + 38535168;           // 100352x1152 bf16
  unsigned short* AOb = XW;                      // attn out (XW dead)
  unsigned short* XN2 = QKV;                     // LN2 out (QKV dead, 77MB)
  unsigned short* H1buf = QKV + 38535168;        // 50176x1536 bf16
  float* XO = (float*)d_out;                     // residual stream in d_out
  float* out = (float*)d_out;

  wt_kernel<<<1728, 256, 0, stream>>>(wqkv, wqkvT, 384, 1152);
  wt_kernel<<<576, 256, 0, stream>>>(wproj, wprojT, 384, 384);
  wt_kernel<<<2304, 256, 0, stream>>>(wfc1, wfc1T, 384, 1536);
  wt_kernel<<<2304, 256, 0, stream>>>(wfc2, wfc2T, 1536, 384);

  ln_kernel<1><<<25088, 256, 0, stream>>>(x, g1, b1, XW);
  gemmP<0><<<392 * 9, 512, 0, stream>>>(XW, wqkvT, bqkv, 384, 9, QKV, nullptr);
  attn_mfma<<<6144, 256, 0, stream>>>(QKV, AOb);
  gemmS<1><<<784 * 3, 256, 0, stream>>>(AOb, wprojT, bproj, 384, 3, XO, x);
  ln_kernel<0><<<25088, 256, 0, stream>>>(XO, g2, b2, XN2);
  for (int ch = 0; ch < 2; ch++) {
    const unsigned short* a2 = XN2 + (size_t)ch * 50176 * 384;
    float* o2 = out + (size_t)ch * 50176 * 384;
    gemmP<2><<<196 * 12, 512, 0, stream>>>(a2, wfc1T, bfc1, 384, 12, H1buf, nullptr);
    gemmS<3><<<392 * 3, 256, 0, stream>>>(H1buf, wfc2T, bfc2, 1536, 3, o2, o2);
  }
}

// Round 19
// 861.625 us; speedup vs baseline: 1.0783x; 1.0157x over previous
//
#include <hip/hip_runtime.h>
#include <math.h>

// SwinBlock on MI355X. Workspace (311.8 MB):
//   W(3.54MB bf16 B^T weights) | XW(77.07MB) | QKV(231.2MB natural [row][1152])
// Aliases: AO=XW, XN2=QKV(first 77MB), H1buf=QKV+38535168. XO lives in d_out.
// R18: 875us best (barrier-free attn).
// R19: (1) 4 wt launches -> 1 fused launch; (2) proj back to gemmP (2.30
//   occupancy-rounds at 16 waves/CU vs gemmS 3.06 at 12); (3) attn drops
//   Qs/Ks zero-fills (garbage only reaches masked/discarded lanes; VT fill
//   stays — P=0 x NaN would poison PV).

typedef float f32x4 __attribute__((ext_vector_type(4)));
typedef float f32x2 __attribute__((ext_vector_type(2)));
typedef __bf16 bf16x8 __attribute__((ext_vector_type(8)));
typedef short s16x8 __attribute__((ext_vector_type(8)));
typedef unsigned short u16x2 __attribute__((ext_vector_type(2)));

#define DEV static __device__ __forceinline__

DEV unsigned short f2bf(float f) {
  unsigned int u = __builtin_bit_cast(unsigned int, f);
  u += 0x7fffu + ((u >> 16) & 1u);
  return (unsigned short)(u >> 16);
}
DEV float bf2f(unsigned short h) {
  unsigned int u = ((unsigned int)h) << 16;
  return __builtin_bit_cast(float, u);
}
DEV void load_lds16(const void* g, void* l) {
  __builtin_amdgcn_global_load_lds(
      (const __attribute__((address_space(1))) unsigned int*)g,
      (__attribute__((address_space(3))) unsigned int*)l, 16, 0, 0);
}

// windowed row r (= win*49 + t, shifted coords) -> natural row in x.
DEV int win_src_row(int row) {
  int win = row / 49, t = row - win * 49;
  int bimg = win >> 6, wrem = win & 63;
  int wy = wrem >> 3, wx = wrem & 7;
  int ti = t / 7, tj = t - ti * 7;
  int hh = wy * 7 + ti, ww = wx * 7 + tj;
  int sh = hh + 3; if (sh >= 56) sh -= 56;
  int sw = ww + 3; if (sw >= 56) sw -= 56;
  return bimg * 3136 + sh * 56 + sw;
}

// ------ fused weight cast+transpose: all 4 weights in one launch -----------
// ranges (elems): wqkv 442368 | wproj 147456 | wfc1 589824 | wfc2 589824
__global__ void wt_all(const float* __restrict__ wqkv, const float* __restrict__ wproj,
                       const float* __restrict__ wfc1, const float* __restrict__ wfc2,
                       unsigned short* __restrict__ wt) {
  int idx = blockIdx.x * 256 + threadIdx.x;
  const float* w;
  int Kd, Nd, off;
  if (idx < 442368) { w = wqkv; Kd = 384; Nd = 1152; off = 0; }
  else if (idx < 589824) { w = wproj; Kd = 384; Nd = 384; off = 442368; }
  else if (idx < 1179648) { w = wfc1; Kd = 384; Nd = 1536; off = 589824; }
  else if (idx < 1769472) { w = wfc2; Kd = 1536; Nd = 384; off = 1179648; }
  else return;
  int li = idx - off;
  int n = li / Kd, k = li - n * Kd;
  wt[idx] = f2bf(w[(size_t)k * Nd + n]);
}

// ---------------- LayerNorm (+ optional shifted-window gather), one wave/row
template <int GATHER>
__global__ __launch_bounds__(256) void ln_kernel(const float* __restrict__ x,
                                                 const float* __restrict__ g,
                                                 const float* __restrict__ bb,
                                                 unsigned short* __restrict__ out) {
  int row = blockIdx.x * 4 + (threadIdx.x >> 6);
  int lane = threadIdx.x & 63;
  int src = GATHER ? win_src_row(row) : row;
  const float* xr = x + (size_t)src * 384;
  f32x2 p0 = *(const f32x2*)(xr + lane * 2);
  f32x2 p1 = *(const f32x2*)(xr + 128 + lane * 2);
  f32x2 p2 = *(const f32x2*)(xr + 256 + lane * 2);
  float s = p0.x + p0.y + p1.x + p1.y + p2.x + p2.y;
  float s2 = p0.x * p0.x + p0.y * p0.y + p1.x * p1.x + p1.y * p1.y +
             p2.x * p2.x + p2.y * p2.y;
#pragma unroll
  for (int off = 32; off; off >>= 1) {
    s += __shfl_xor(s, off);
    s2 += __shfl_xor(s2, off);
  }
  float mu = s * (1.0f / 384.0f);
  float rs = rsqrtf(s2 * (1.0f / 384.0f) - mu * mu + 1e-5f);
  unsigned short* orow = out + (size_t)row * 384;
  int c = lane * 2;
  u16x2 o;
  o.x = f2bf((p0.x - mu) * rs * g[c] + bb[c]);
  o.y = f2bf((p0.y - mu) * rs * g[c + 1] + bb[c + 1]);
  *(u16x2*)(orow + c) = o;
  c += 128;
  o.x = f2bf((p1.x - mu) * rs * g[c] + bb[c]);
  o.y = f2bf((p1.y - mu) * rs * g[c + 1] + bb[c + 1]);
  *(u16x2*)(orow + c) = o;
  c += 128;
  o.x = f2bf((p2.x - mu) * rs * g[c] + bb[c]);
  o.y = f2bf((p2.y - mu) * rs * g[c + 1] + bb[c + 1]);
  *(u16x2*)(orow + c) = o;
}

// ================= gemmP: 256x128 BK=32, NB=3 (proven) =====================
// 512 thr / 8 waves (4M x 2N), per-wave 64x64. 72KB LDS -> 2 blocks/CU.
// EPI 0: +bqkv bf16 s1152 | EPI 1: +bproj +res inv-window f32 |
// EPI 2: +bfc1 GELU bf16 s1536
template <int EPI>
__global__ __launch_bounds__(512, 4) void gemmP(const unsigned short* __restrict__ A,
                                                const unsigned short* __restrict__ BT,
                                                const float* __restrict__ bias, int Kd,
                                                int nTilesN, void* __restrict__ out0,
                                                const float* __restrict__ res) {
  constexpr int BM = 256, BN = 128, BK = 32;
  __shared__ __attribute__((aligned(16))) unsigned short As[3][BM * BK];
  __shared__ __attribute__((aligned(16))) unsigned short Bs[3][BN * BK];
  const int tid = threadIdx.x;
  const int wid = tid >> 6, lane = tid & 63;
  const int nwg = gridDim.x;
  const int xcd = blockIdx.x & 7, loc = blockIdx.x >> 3;
  const int q = nwg >> 3, rr = nwg & 7;
  const int swz = (xcd < rr ? xcd * (q + 1) : rr * (q + 1) + (xcd - rr) * q) + loc;
  const int bm = swz / nTilesN, bn = swz - bm * nTilesN;
  const int wr = wid >> 1, wc = wid & 1;
  f32x4 acc[4][4] = {};
  const int srow = tid >> 2;
  const int chunk = (tid & 3) ^ ((tid >> 3) & 3);
  const unsigned short* gA0 = A + (size_t)(bm * BM + srow) * Kd + chunk * 8;
  const unsigned short* gB0 = BT + (size_t)(bn * BN + srow) * Kd + chunk * 8;
  const size_t rowstep = (size_t)128 * Kd;

  auto STAGE = [&](int b, int t) {
    const int k0 = t << 5;
    unsigned short* lA = &As[b][tid * 8];
    load_lds16(gA0 + k0, lA);
    load_lds16(gA0 + k0 + rowstep, lA + 4096);
    load_lds16(gB0 + k0, &Bs[b][tid * 8]);
  };

  const int frow = lane & 15, g = lane >> 4;
  const int rslot = (g ^ ((frow >> 1) & 3)) << 3;
  const int aBase = (wr * 64 + frow) * BK + rslot;
  const int bBase = (wc * 64 + frow) * BK + rslot;

  const int nk = Kd >> 5;
  {
    unsigned short* lA = &As[0][tid * 8];
    load_lds16(gA0, lA);
    load_lds16(gA0 + rowstep, lA + 4096);
    load_lds16(gB0, &Bs[0][tid * 8]);
    unsigned short* lA1 = &As[1][tid * 8];
    load_lds16(gA0 + 32, lA1);
    load_lds16(gA0 + 32 + rowstep, lA1 + 4096);
    load_lds16(gB0 + 32, &Bs[1][tid * 8]);
  }
  asm volatile("s_waitcnt vmcnt(3)");
  __builtin_amdgcn_sched_barrier(0);
  __builtin_amdgcn_s_barrier();
  int b = 0;
  for (int t = 0; t < nk; ++t) {
    const int bst = (b == 0) ? 2 : b - 1;
    const int k0n = (t + 2) << 5;
    const unsigned short* Ab = As[b];
    const unsigned short* Bb = Bs[b];
    __builtin_amdgcn_sched_barrier(0);
    bf16x8 af[4], bfr[2];
#pragma unroll
    for (int m = 0; m < 4; m++) af[m] = *(const bf16x8*)(Ab + aBase + m * 16 * BK);
#pragma unroll
    for (int n = 0; n < 2; n++) bfr[n] = *(const bf16x8*)(Bb + bBase + n * 16 * BK);
    if (t + 2 < nk) {
      unsigned short* lA = &As[bst][tid * 8];
      load_lds16(gA0 + k0n, lA);
      load_lds16(gA0 + k0n + rowstep, lA + 4096);
    }
    __builtin_amdgcn_sched_barrier(0);
    __builtin_amdgcn_s_barrier();
    asm volatile("s_waitcnt lgkmcnt(0)");
    __builtin_amdgcn_sched_barrier(0);
    __builtin_amdgcn_s_setprio(1);
#pragma unroll
    for (int m = 0; m < 4; m++)
#pragma unroll
      for (int n = 0; n < 2; n++)
        acc[m][n] = __builtin_amdgcn_mfma_f32_16x16x32_bf16(af[m], bfr[n], acc[m][n], 0, 0, 0);
    __builtin_amdgcn_s_setprio(0);
    __builtin_amdgcn_sched_barrier(0);
    __builtin_amdgcn_s_barrier();
    bf16x8 bfr2[2];
#pragma unroll
    for (int n = 0; n < 2; n++)
      bfr2[n] = *(const bf16x8*)(Bb + bBase + (n + 2) * 16 * BK);
    if (t + 2 < nk) load_lds16(gB0 + k0n, &Bs[bst][tid * 8]);
    __builtin_amdgcn_sched_barrier(0);
    __builtin_amdgcn_s_barrier();
    asm volatile("s_waitcnt lgkmcnt(0)");
    __builtin_amdgcn_sched_barrier(0);
    __builtin_amdgcn_s_setprio(1);
#pragma unroll
    for (int m = 0; m < 4; m++)
#pragma unroll
      for (int n = 0; n < 2; n++)
        acc[m][n + 2] = __builtin_amdgcn_mfma_f32_16x16x32_bf16(af[m], bfr2[n], acc[m][n + 2], 0, 0, 0);
    __builtin_amdgcn_s_setprio(0);
    __builtin_amdgcn_sched_barrier(0);
    if (t + 1 < nk) {
      if (t + 2 < nk) asm volatile("s_waitcnt vmcnt(3)");
      else asm volatile("s_waitcnt vmcnt(0)");
      __builtin_amdgcn_sched_barrier(0);
    }
    __builtin_amdgcn_s_barrier();
    b = (b == 2) ? 0 : b + 1;
  }
  const int rbase = bm * BM + wr * 64 + (g << 2);
  const int cbase = bn * BN + wc * 64 + frow;
#pragma unroll
  for (int m = 0; m < 4; m++) {
#pragma unroll
    for (int j = 0; j < 4; j++) {
      const int r = rbase + m * 16 + j;
      if constexpr (EPI == 0) {
        unsigned short* C = (unsigned short*)out0;
        size_t ro = (size_t)r * 1152;
#pragma unroll
        for (int n = 0; n < 4; n++) {
          int cc = cbase + n * 16;
          C[ro + cc] = f2bf(acc[m][n][j] + bias[cc]);
        }
      } else if constexpr (EPI == 1) {
        float* XO = (float*)out0;
        size_t srowo = (size_t)win_src_row(r) * 384;
#pragma unroll
        for (int n = 0; n < 4; n++) {
          int cc = cbase + n * 16;
          XO[srowo + cc] = acc[m][n][j] + bias[cc] + res[srowo + cc];
        }
      } else if constexpr (EPI == 2) {
        unsigned short* H1 = (unsigned short*)out0;
        size_t ro = (size_t)r * 1536;
#pragma unroll
        for (int n = 0; n < 4; n++) {
          int cc = cbase + n * 16;
          float u = acc[m][n][j] + bias[cc];
          H1[ro + cc] = f2bf(0.5f * u * (1.0f + erff(u * 0.70710678118654752f)));
        }
      }
    }
  }
}

// ================= gemmS: BM=128, NB=3, 48KB (FC2) =========================
// 256 thr / 4 waves (2M x 2N). EPI 3: +bfc2 + in-place residual f32 (s384).
template <int EPI>
__global__ __launch_bounds__(256, 3) void gemmS(const unsigned short* __restrict__ A,
                                                const unsigned short* __restrict__ BT,
                                                const float* __restrict__ bias, int Kd,
                                                int nTilesN, void* __restrict__ out0,
                                                const float* __restrict__ res) {
  constexpr int BM = 128, BN = 128, BK = 32;
  __shared__ __attribute__((aligned(16))) unsigned short As[3][BM * BK];
  __shared__ __attribute__((aligned(16))) unsigned short Bs[3][BN * BK];
  const int tid = threadIdx.x;
  const int wid = tid >> 6, lane = tid & 63;
  const int nwg = gridDim.x;
  const int xcd = blockIdx.x & 7, loc = blockIdx.x >> 3;
  const int q = nwg >> 3, rr = nwg & 7;
  const int swz = (xcd < rr ? xcd * (q + 1) : rr * (q + 1) + (xcd - rr) * q) + loc;
  const int bm = swz / nTilesN, bn = swz - bm * nTilesN;
  const int wr = wid >> 1, wc = wid & 1;
  f32x4 acc[4][4] = {};
  const int srow = tid >> 2;
  const int chunk = (tid & 3) ^ ((tid >> 3) & 3);
  const unsigned short* gA0 = A + (size_t)(bm * BM + srow) * Kd + chunk * 8;
  const unsigned short* gB0 = BT + (size_t)(bn * BN + srow) * Kd + chunk * 8;
  const size_t rowstep = (size_t)64 * Kd;

  auto STAGE = [&](int b, int t) {
    const int k0 = t << 5;
    unsigned short* lA = &As[b][tid * 8];
    unsigned short* lB = &Bs[b][tid * 8];
    load_lds16(gA0 + k0, lA);
    load_lds16(gA0 + k0 + rowstep, lA + 2048);
    load_lds16(gB0 + k0, lB);
    load_lds16(gB0 + k0 + rowstep, lB + 2048);
  };

  const int frow = lane & 15, g = lane >> 4;
  const int rslot = (g ^ ((frow >> 1) & 3)) << 3;
  const int aBase = (wr * 64 + frow) * BK + rslot;
  const int bBase = (wc * 64 + frow) * BK + rslot;

  const int nk = Kd >> 5;  // 48
  STAGE(0, 0);
  STAGE(1, 1);
  asm volatile("s_waitcnt vmcnt(4)");
  __builtin_amdgcn_sched_barrier(0);
  __builtin_amdgcn_s_barrier();
  int b = 0;
  for (int t = 0; t < nk; ++t) {
    const int bst = (b == 0) ? 2 : b - 1;
    const unsigned short* Ab = As[b];
    const unsigned short* Bb = Bs[b];
    __builtin_amdgcn_sched_barrier(0);
    bf16x8 af[4], bfr[2];
#pragma unroll
    for (int m = 0; m < 4; m++) af[m] = *(const bf16x8*)(Ab + aBase + m * 16 * BK);
#pragma unroll
    for (int n = 0; n < 2; n++) bfr[n] = *(const bf16x8*)(Bb + bBase + n * 16 * BK);
    if (t + 2 < nk) {
      const int k0n = (t + 2) << 5;
      unsigned short* lA = &As[bst][tid * 8];
      load_lds16(gA0 + k0n, lA);
      load_lds16(gA0 + k0n + rowstep, lA + 2048);
    }
    __builtin_amdgcn_sched_barrier(0);
    __builtin_amdgcn_s_barrier();
    asm volatile("s_waitcnt lgkmcnt(0)");
    __builtin_amdgcn_sched_barrier(0);
    __builtin_amdgcn_s_setprio(1);
#pragma unroll
    for (int m = 0; m < 4; m++)
#pragma unroll
      for (int n = 0; n < 2; n++)
        acc[m][n] = __builtin_amdgcn_mfma_f32_16x16x32_bf16(af[m], bfr[n], acc[m][n], 0, 0, 0);
    __builtin_amdgcn_s_setprio(0);
    __builtin_amdgcn_sched_barrier(0);
    __builtin_amdgcn_s_barrier();
    bf16x8 bfr2[2];
#pragma unroll
    for (int n = 0; n < 2; n++)
      bfr2[n] = *(const bf16x8*)(Bb + bBase + (n + 2) * 16 * BK);
    if (t + 2 < nk) {
      const int k0n = (t + 2) << 5;
      unsigned short* lB = &Bs[bst][tid * 8];
      load_lds16(gB0 + k0n, lB);
      load_lds16(gB0 + k0n + rowstep, lB + 2048);
    }
    __builtin_amdgcn_sched_barrier(0);
    __builtin_amdgcn_s_barrier();
    asm volatile("s_waitcnt lgkmcnt(0)");
    __builtin_amdgcn_sched_barrier(0);
    __builtin_amdgcn_s_setprio(1);
#pragma unroll
    for (int m = 0; m < 4; m++)
#pragma unroll
      for (int n = 0; n < 2; n++)
        acc[m][n + 2] = __builtin_amdgcn_mfma_f32_16x16x32_bf16(af[m], bfr2[n], acc[m][n + 2], 0, 0, 0);
    __builtin_amdgcn_s_setprio(0);
    __builtin_amdgcn_sched_barrier(0);
    if (t + 1 < nk) {
      if (t + 2 < nk) asm volatile("s_waitcnt vmcnt(4)");
      else asm volatile("s_waitcnt vmcnt(0)");
      __builtin_amdgcn_sched_barrier(0);
    }
    __builtin_amdgcn_s_barrier();
    b = (b == 2) ? 0 : b + 1;
  }
  const int rbase = bm * BM + wr * 64 + (g << 2);
  const int cbase = bn * BN + wc * 64 + frow;
#pragma unroll
  for (int m = 0; m < 4; m++) {
#pragma unroll
    for (int j = 0; j < 4; j++) {
      const int r = rbase + m * 16 + j;
      float* O = (float*)out0;
      size_t ro = (size_t)r * 384;
#pragma unroll
      for (int n = 0; n < 4; n++) {
        int cc = cbase + n * 16;
        O[ro + cc] = acc[m][n][j] + bias[cc] + res[ro + cc];
      }
    }
  }
}

// ---------------- MFMA attention: 4 waves/block, wave-private LDS ----------
// No __syncthreads: all LDS traffic is intra-wave (lgkmcnt-ordered).
// Qs/Ks rows >=49 left garbage (only reach masked/discarded outputs);
// VT cols 49..63 MUST be zeroed (P=0 x NaN would poison PV).
__global__ __launch_bounds__(256) void attn_mfma(const unsigned short* __restrict__ QKV,
                                                 unsigned short* __restrict__ AO) {
  __shared__ __attribute__((aligned(16))) unsigned short L[4][7168];
  const int wid = threadIdx.x >> 6, lane = threadIdx.x & 63;
  const int blk = blockIdx.x * 4 + wid;
  const int win = blk / 12, head = blk - win * 12;
  unsigned short* Qs = L[wid];
  unsigned short* Ks = Qs + 2048;
  unsigned short* VT = Qs + 4096;
  unsigned short* Ps = Qs + 6144;
  const unsigned short* Qp = QKV + (size_t)win * 49 * 1152 + head * 32;
  for (int i = lane; i < 196; i += 64) {
    int row = i >> 2, c8 = (i & 3) << 3;
    const unsigned short* base = Qp + (size_t)row * 1152 + c8;
    *(s16x8*)(Qs + row * 32 + c8) = *(const s16x8*)(base);
    *(s16x8*)(Ks + row * 32 + c8) = *(const s16x8*)(base + 384);
    s16x8 vv = *(const s16x8*)(base + 768);
#pragma unroll
    for (int u = 0; u < 8; u++) VT[(c8 + u) * 64 + row] = (unsigned short)vv[u];
  }
  for (int i = lane; i < 480; i += 64) {
    int d = i / 15, k = 49 + (i - d * 15);
    VT[d * 64 + k] = 0;
  }

  const int g = lane >> 4, qi = lane & 15;
  const float scale = 0.17677669529663689f;
  bf16x8 kf[4];
#pragma unroll
  for (int mt = 0; mt < 4; mt++)
    kf[mt] = *(const bf16x8*)(Ks + (mt * 16 + qi) * 32 + g * 8);

  for (int nt = 0; nt < 4; nt++) {
    bf16x8 qf = *(const bf16x8*)(Qs + (nt * 16 + qi) * 32 + g * 8);
    f32x4 st[4];
#pragma unroll
    for (int mt = 0; mt < 4; mt++) {
      f32x4 zz = {};
      st[mt] = __builtin_amdgcn_mfma_f32_16x16x32_bf16(kf[mt], qf, zz, 0, 0, 0);
    }
    float m = -1e30f;
#pragma unroll
    for (int mt = 0; mt < 3; mt++)
#pragma unroll
      for (int j = 0; j < 4; j++) m = fmaxf(m, st[mt][j]);
    if (g == 0) m = fmaxf(m, st[3][0]);
    m = fmaxf(m, __shfl_xor(m, 16));
    m = fmaxf(m, __shfl_xor(m, 32));
    m *= scale;
    float p[4][4];
    float sum = 0.f;
#pragma unroll
    for (int mt = 0; mt < 4; mt++)
#pragma unroll
      for (int j = 0; j < 4; j++) {
        int k = mt * 16 + g * 4 + j;
        float e = (k < 49) ? __expf(st[mt][j] * scale - m) : 0.f;
        p[mt][j] = e;
        sum += e;
      }
    sum += __shfl_xor(sum, 16);
    sum += __shfl_xor(sum, 32);
    float inv = 1.0f / sum;
#pragma unroll
    for (int mt = 0; mt < 4; mt++)
#pragma unroll
      for (int j = 0; j < 4; j += 2) {
        unsigned int pk = (unsigned int)f2bf(p[mt][j]) |
                          ((unsigned int)f2bf(p[mt][j + 1]) << 16);
        *(unsigned int*)(Ps + qi * 64 + mt * 16 + g * 4 + j) = pk;
      }
    f32x4 acc0 = {}, acc1 = {};
#pragma unroll
    for (int kt = 0; kt < 2; kt++) {
      bf16x8 pa = *(const bf16x8*)(Ps + qi * 64 + kt * 32 + g * 8);
      bf16x8 vb0 = *(const bf16x8*)(VT + qi * 64 + kt * 32 + g * 8);
      bf16x8 vb1 = *(const bf16x8*)(VT + (16 + qi) * 64 + kt * 32 + g * 8);
      acc0 = __builtin_amdgcn_mfma_f32_16x16x32_bf16(pa, vb0, acc0, 0, 0, 0);
      acc1 = __builtin_amdgcn_mfma_f32_16x16x32_bf16(pa, vb1, acc1, 0, 0, 0);
    }
#pragma unroll
    for (int jr = 0; jr < 4; jr++) {
      int q2 = g * 4 + jr;
      int qg = nt * 16 + q2;
      float iv = __shfl(inv, q2);
      if (qg < 49) {
        unsigned short* op = AO + ((size_t)win * 49 + qg) * 384 + head * 32 + qi;
        op[0] = f2bf(acc0[jr] * iv);
        op[16] = f2bf(acc1[jr] * iv);
      }
    }
  }
}

extern "C" void kernel_launch(void* const* d_in, const int* in_sizes, int n_in,
                              void* d_out, int out_size, void* d_ws, size_t ws_size,
                              hipStream_t stream) {
  (void)in_sizes; (void)n_in; (void)out_size; (void)ws_size;
  const float* x = (const float*)d_in[0];
  const float* g1 = (const float*)d_in[3];
  const float* b1 = (const float*)d_in[4];
  const float* wqkv = (const float*)d_in[5];
  const float* bqkv = (const float*)d_in[6];
  const float* wproj = (const float*)d_in[7];
  const float* bproj = (const float*)d_in[8];
  const float* g2 = (const float*)d_in[9];
  const float* b2 = (const float*)d_in[10];
  const float* wfc1 = (const float*)d_in[11];
  const float* bfc1 = (const float*)d_in[12];
  const float* wfc2 = (const float*)d_in[13];
  const float* bfc2 = (const float*)d_in[14];

  char* ws = (char*)d_ws;
  unsigned short* wtbuf = (unsigned short*)ws;   // all 4 B^T weights, packed
  unsigned short* wqkvT = wtbuf;                 // [1152][384] @ 0
  unsigned short* wprojT = wtbuf + 442368;       // [384][384]
  unsigned short* wfc1T = wtbuf + 589824;        // [1536][384]
  unsigned short* wfc2T = wtbuf + 1179648;       // [384][1536]
  unsigned short* XW = wtbuf + 1769472;          // 100352x384 bf16
  unsigned short* QKV = XW + 38535168;           // 100352x1152 bf16
  unsigned short* AOb = XW;                      // attn out (XW dead)
  unsigned short* XN2 = QKV;                     // LN2 out (QKV dead, 77MB)
  unsigned short* H1buf = QKV + 38535168;        // 50176x1536 bf16
  float* XO = (float*)d_out;                     // residual stream in d_out
  float* out = (float*)d_out;

  wt_all<<<6912, 256, 0, stream>>>(wqkv, wproj, wfc1, wfc2, wtbuf);

  ln_kernel<1><<<25088, 256, 0, stream>>>(x, g1, b1, XW);
  gemmP<0><<<392 * 9, 512, 0, stream>>>(XW, wqkvT, bqkv, 384, 9, QKV, nullptr);
  attn_mfma<<<6144, 256, 0, stream>>>(QKV, AOb);
  gemmP<1><<<392 * 3, 512, 0, stream>>>(AOb, wprojT, bproj, 384, 3, XO, x);
  ln_kernel<0><<<25088, 256, 0, stream>>>(XO, g2, b2, XN2);
  for (int ch = 0; ch < 2; ch++) {
    const unsigned short* a2 = XN2 + (size_t)ch * 50176 * 384;
    float* o2 = out + (size_t)ch * 50176 * 384;
    gemmP<2><<<196 * 12, 512, 0, stream>>>(a2, wfc1T, bfc1, 384, 12, H1buf, nullptr);
    gemmS<3><<<392 * 3, 256, 0, stream>>>(H1buf, wfc2T, bfc2, 1536, 3, o2, o2);
  }
}

// Round 20
// 842.557 us; speedup vs baseline: 1.1027x; 1.0226x over previous
//
#include <hip/hip_runtime.h>
#include <math.h>

// SwinBlock on MI355X. Workspace (311.8 MB):
//   W(3.54MB bf16 B^T weights) | XW(77.07MB) | QKV(231.2MB natural [row][1152])
// Aliases: AO=XW, XN2=QKV(first 77MB), H1buf=QKV+38535168. XO lives in d_out.
// R19: 861us best.
// R20: attn drops Qs/Ks LDS staging entirely — Q/K fragments are row-indexed
//   by lane, so each lane loads its 16B straight from global (rows clamped to
//   48; duplicates are masked). LDS/wave 14KB -> 6KB => 2 -> 6 blocks/CU
//   (3x occupancy on a latency-bound kernel). V transpose staging stays.

typedef float f32x4 __attribute__((ext_vector_type(4)));
typedef float f32x2 __attribute__((ext_vector_type(2)));
typedef __bf16 bf16x8 __attribute__((ext_vector_type(8)));
typedef short s16x8 __attribute__((ext_vector_type(8)));
typedef unsigned short u16x2 __attribute__((ext_vector_type(2)));

#define DEV static __device__ __forceinline__

DEV unsigned short f2bf(float f) {
  unsigned int u = __builtin_bit_cast(unsigned int, f);
  u += 0x7fffu + ((u >> 16) & 1u);
  return (unsigned short)(u >> 16);
}
DEV float bf2f(unsigned short h) {
  unsigned int u = ((unsigned int)h) << 16;
  return __builtin_bit_cast(float, u);
}
DEV void load_lds16(const void* g, void* l) {
  __builtin_amdgcn_global_load_lds(
      (const __attribute__((address_space(1))) unsigned int*)g,
      (__attribute__((address_space(3))) unsigned int*)l, 16, 0, 0);
}

// windowed row r (= win*49 + t, shifted coords) -> natural row in x.
DEV int win_src_row(int row) {
  int win = row / 49, t = row - win * 49;
  int bimg = win >> 6, wrem = win & 63;
  int wy = wrem >> 3, wx = wrem & 7;
  int ti = t / 7, tj = t - ti * 7;
  int hh = wy * 7 + ti, ww = wx * 7 + tj;
  int sh = hh + 3; if (sh >= 56) sh -= 56;
  int sw = ww + 3; if (sw >= 56) sw -= 56;
  return bimg * 3136 + sh * 56 + sw;
}

// ------ fused weight cast+transpose: all 4 weights in one launch -----------
__global__ void wt_all(const float* __restrict__ wqkv, const float* __restrict__ wproj,
                       const float* __restrict__ wfc1, const float* __restrict__ wfc2,
                       unsigned short* __restrict__ wt) {
  int idx = blockIdx.x * 256 + threadIdx.x;
  const float* w;
  int Kd, Nd, off;
  if (idx < 442368) { w = wqkv; Kd = 384; Nd = 1152; off = 0; }
  else if (idx < 589824) { w = wproj; Kd = 384; Nd = 384; off = 442368; }
  else if (idx < 1179648) { w = wfc1; Kd = 384; Nd = 1536; off = 589824; }
  else if (idx < 1769472) { w = wfc2; Kd = 1536; Nd = 384; off = 1179648; }
  else return;
  int li = idx - off;
  int n = li / Kd, k = li - n * Kd;
  wt[idx] = f2bf(w[(size_t)k * Nd + n]);
}

// ---------------- LayerNorm (+ optional shifted-window gather), one wave/row
template <int GATHER>
__global__ __launch_bounds__(256) void ln_kernel(const float* __restrict__ x,
                                                 const float* __restrict__ g,
                                                 const float* __restrict__ bb,
                                                 unsigned short* __restrict__ out) {
  int row = blockIdx.x * 4 + (threadIdx.x >> 6);
  int lane = threadIdx.x & 63;
  int src = GATHER ? win_src_row(row) : row;
  const float* xr = x + (size_t)src * 384;
  f32x2 p0 = *(const f32x2*)(xr + lane * 2);
  f32x2 p1 = *(const f32x2*)(xr + 128 + lane * 2);
  f32x2 p2 = *(const f32x2*)(xr + 256 + lane * 2);
  float s = p0.x + p0.y + p1.x + p1.y + p2.x + p2.y;
  float s2 = p0.x * p0.x + p0.y * p0.y + p1.x * p1.x + p1.y * p1.y +
             p2.x * p2.x + p2.y * p2.y;
#pragma unroll
  for (int off = 32; off; off >>= 1) {
    s += __shfl_xor(s, off);
    s2 += __shfl_xor(s2, off);
  }
  float mu = s * (1.0f / 384.0f);
  float rs = rsqrtf(s2 * (1.0f / 384.0f) - mu * mu + 1e-5f);
  unsigned short* orow = out + (size_t)row * 384;
  int c = lane * 2;
  u16x2 o;
  o.x = f2bf((p0.x - mu) * rs * g[c] + bb[c]);
  o.y = f2bf((p0.y - mu) * rs * g[c + 1] + bb[c + 1]);
  *(u16x2*)(orow + c) = o;
  c += 128;
  o.x = f2bf((p1.x - mu) * rs * g[c] + bb[c]);
  o.y = f2bf((p1.y - mu) * rs * g[c + 1] + bb[c + 1]);
  *(u16x2*)(orow + c) = o;
  c += 128;
  o.x = f2bf((p2.x - mu) * rs * g[c] + bb[c]);
  o.y = f2bf((p2.y - mu) * rs * g[c + 1] + bb[c + 1]);
  *(u16x2*)(orow + c) = o;
}

// ================= gemmP: 256x128 BK=32, NB=3 (proven) =====================
template <int EPI>
__global__ __launch_bounds__(512, 4) void gemmP(const unsigned short* __restrict__ A,
                                                const unsigned short* __restrict__ BT,
                                                const float* __restrict__ bias, int Kd,
                                                int nTilesN, void* __restrict__ out0,
                                                const float* __restrict__ res) {
  constexpr int BM = 256, BN = 128, BK = 32;
  __shared__ __attribute__((aligned(16))) unsigned short As[3][BM * BK];
  __shared__ __attribute__((aligned(16))) unsigned short Bs[3][BN * BK];
  const int tid = threadIdx.x;
  const int wid = tid >> 6, lane = tid & 63;
  const int nwg = gridDim.x;
  const int xcd = blockIdx.x & 7, loc = blockIdx.x >> 3;
  const int q = nwg >> 3, rr = nwg & 7;
  const int swz = (xcd < rr ? xcd * (q + 1) : rr * (q + 1) + (xcd - rr) * q) + loc;
  const int bm = swz / nTilesN, bn = swz - bm * nTilesN;
  const int wr = wid >> 1, wc = wid & 1;
  f32x4 acc[4][4] = {};
  const int srow = tid >> 2;
  const int chunk = (tid & 3) ^ ((tid >> 3) & 3);
  const unsigned short* gA0 = A + (size_t)(bm * BM + srow) * Kd + chunk * 8;
  const unsigned short* gB0 = BT + (size_t)(bn * BN + srow) * Kd + chunk * 8;
  const size_t rowstep = (size_t)128 * Kd;

  auto STAGE = [&](int b, int t) {
    const int k0 = t << 5;
    unsigned short* lA = &As[b][tid * 8];
    load_lds16(gA0 + k0, lA);
    load_lds16(gA0 + k0 + rowstep, lA + 4096);
    load_lds16(gB0 + k0, &Bs[b][tid * 8]);
  };

  const int frow = lane & 15, g = lane >> 4;
  const int rslot = (g ^ ((frow >> 1) & 3)) << 3;
  const int aBase = (wr * 64 + frow) * BK + rslot;
  const int bBase = (wc * 64 + frow) * BK + rslot;

  const int nk = Kd >> 5;
  {
    unsigned short* lA = &As[0][tid * 8];
    load_lds16(gA0, lA);
    load_lds16(gA0 + rowstep, lA + 4096);
    load_lds16(gB0, &Bs[0][tid * 8]);
    unsigned short* lA1 = &As[1][tid * 8];
    load_lds16(gA0 + 32, lA1);
    load_lds16(gA0 + 32 + rowstep, lA1 + 4096);
    load_lds16(gB0 + 32, &Bs[1][tid * 8]);
  }
  asm volatile("s_waitcnt vmcnt(3)");
  __builtin_amdgcn_sched_barrier(0);
  __builtin_amdgcn_s_barrier();
  int b = 0;
  for (int t = 0; t < nk; ++t) {
    const int bst = (b == 0) ? 2 : b - 1;
    const int k0n = (t + 2) << 5;
    const unsigned short* Ab = As[b];
    const unsigned short* Bb = Bs[b];
    __builtin_amdgcn_sched_barrier(0);
    bf16x8 af[4], bfr[2];
#pragma unroll
    for (int m = 0; m < 4; m++) af[m] = *(const bf16x8*)(Ab + aBase + m * 16 * BK);
#pragma unroll
    for (int n = 0; n < 2; n++) bfr[n] = *(const bf16x8*)(Bb + bBase + n * 16 * BK);
    if (t + 2 < nk) {
      unsigned short* lA = &As[bst][tid * 8];
      load_lds16(gA0 + k0n, lA);
      load_lds16(gA0 + k0n + rowstep, lA + 4096);
    }
    __builtin_amdgcn_sched_barrier(0);
    __builtin_amdgcn_s_barrier();
    asm volatile("s_waitcnt lgkmcnt(0)");
    __builtin_amdgcn_sched_barrier(0);
    __builtin_amdgcn_s_setprio(1);
#pragma unroll
    for (int m = 0; m < 4; m++)
#pragma unroll
      for (int n = 0; n < 2; n++)
        acc[m][n] = __builtin_amdgcn_mfma_f32_16x16x32_bf16(af[m], bfr[n], acc[m][n], 0, 0, 0);
    __builtin_amdgcn_s_setprio(0);
    __builtin_amdgcn_sched_barrier(0);
    __builtin_amdgcn_s_barrier();
    bf16x8 bfr2[2];
#pragma unroll
    for (int n = 0; n < 2; n++)
      bfr2[n] = *(const bf16x8*)(Bb + bBase + (n + 2) * 16 * BK);
    if (t + 2 < nk) load_lds16(gB0 + k0n, &Bs[bst][tid * 8]);
    __builtin_amdgcn_sched_barrier(0);
    __builtin_amdgcn_s_barrier();
    asm volatile("s_waitcnt lgkmcnt(0)");
    __builtin_amdgcn_sched_barrier(0);
    __builtin_amdgcn_s_setprio(1);
#pragma unroll
    for (int m = 0; m < 4; m++)
#pragma unroll
      for (int n = 0; n < 2; n++)
        acc[m][n + 2] = __builtin_amdgcn_mfma_f32_16x16x32_bf16(af[m], bfr2[n], acc[m][n + 2], 0, 0, 0);
    __builtin_amdgcn_s_setprio(0);
    __builtin_amdgcn_sched_barrier(0);
    if (t + 1 < nk) {
      if (t + 2 < nk) asm volatile("s_waitcnt vmcnt(3)");
      else asm volatile("s_waitcnt vmcnt(0)");
      __builtin_amdgcn_sched_barrier(0);
    }
    __builtin_amdgcn_s_barrier();
    b = (b == 2) ? 0 : b + 1;
  }
  const int rbase = bm * BM + wr * 64 + (g << 2);
  const int cbase = bn * BN + wc * 64 + frow;
#pragma unroll
  for (int m = 0; m < 4; m++) {
#pragma unroll
    for (int j = 0; j < 4; j++) {
      const int r = rbase + m * 16 + j;
      if constexpr (EPI == 0) {
        unsigned short* C = (unsigned short*)out0;
        size_t ro = (size_t)r * 1152;
#pragma unroll
        for (int n = 0; n < 4; n++) {
          int cc = cbase + n * 16;
          C[ro + cc] = f2bf(acc[m][n][j] + bias[cc]);
        }
      } else if constexpr (EPI == 1) {
        float* XO = (float*)out0;
        size_t srowo = (size_t)win_src_row(r) * 384;
#pragma unroll
        for (int n = 0; n < 4; n++) {
          int cc = cbase + n * 16;
          XO[srowo + cc] = acc[m][n][j] + bias[cc] + res[srowo + cc];
        }
      } else if constexpr (EPI == 2) {
        unsigned short* H1 = (unsigned short*)out0;
        size_t ro = (size_t)r * 1536;
#pragma unroll
        for (int n = 0; n < 4; n++) {
          int cc = cbase + n * 16;
          float u = acc[m][n][j] + bias[cc];
          H1[ro + cc] = f2bf(0.5f * u * (1.0f + erff(u * 0.70710678118654752f)));
        }
      }
    }
  }
}

// ================= gemmS: BM=128, NB=3, 48KB (FC2) =========================
template <int EPI>
__global__ __launch_bounds__(256, 3) void gemmS(const unsigned short* __restrict__ A,
                                                const unsigned short* __restrict__ BT,
                                                const float* __restrict__ bias, int Kd,
                                                int nTilesN, void* __restrict__ out0,
                                                const float* __restrict__ res) {
  constexpr int BM = 128, BN = 128, BK = 32;
  __shared__ __attribute__((aligned(16))) unsigned short As[3][BM * BK];
  __shared__ __attribute__((aligned(16))) unsigned short Bs[3][BN * BK];
  const int tid = threadIdx.x;
  const int wid = tid >> 6, lane = tid & 63;
  const int nwg = gridDim.x;
  const int xcd = blockIdx.x & 7, loc = blockIdx.x >> 3;
  const int q = nwg >> 3, rr = nwg & 7;
  const int swz = (xcd < rr ? xcd * (q + 1) : rr * (q + 1) + (xcd - rr) * q) + loc;
  const int bm = swz / nTilesN, bn = swz - bm * nTilesN;
  const int wr = wid >> 1, wc = wid & 1;
  f32x4 acc[4][4] = {};
  const int srow = tid >> 2;
  const int chunk = (tid & 3) ^ ((tid >> 3) & 3);
  const unsigned short* gA0 = A + (size_t)(bm * BM + srow) * Kd + chunk * 8;
  const unsigned short* gB0 = BT + (size_t)(bn * BN + srow) * Kd + chunk * 8;
  const size_t rowstep = (size_t)64 * Kd;

  auto STAGE = [&](int b, int t) {
    const int k0 = t << 5;
    unsigned short* lA = &As[b][tid * 8];
    unsigned short* lB = &Bs[b][tid * 8];
    load_lds16(gA0 + k0, lA);
    load_lds16(gA0 + k0 + rowstep, lA + 2048);
    load_lds16(gB0 + k0, lB);
    load_lds16(gB0 + k0 + rowstep, lB + 2048);
  };

  const int frow = lane & 15, g = lane >> 4;
  const int rslot = (g ^ ((frow >> 1) & 3)) << 3;
  const int aBase = (wr * 64 + frow) * BK + rslot;
  const int bBase = (wc * 64 + frow) * BK + rslot;

  const int nk = Kd >> 5;  // 48
  STAGE(0, 0);
  STAGE(1, 1);
  asm volatile("s_waitcnt vmcnt(4)");
  __builtin_amdgcn_sched_barrier(0);
  __builtin_amdgcn_s_barrier();
  int b = 0;
  for (int t = 0; t < nk; ++t) {
    const int bst = (b == 0) ? 2 : b - 1;
    const unsigned short* Ab = As[b];
    const unsigned short* Bb = Bs[b];
    __builtin_amdgcn_sched_barrier(0);
    bf16x8 af[4], bfr[2];
#pragma unroll
    for (int m = 0; m < 4; m++) af[m] = *(const bf16x8*)(Ab + aBase + m * 16 * BK);
#pragma unroll
    for (int n = 0; n < 2; n++) bfr[n] = *(const bf16x8*)(Bb + bBase + n * 16 * BK);
    if (t + 2 < nk) {
      const int k0n = (t + 2) << 5;
      unsigned short* lA = &As[bst][tid * 8];
      load_lds16(gA0 + k0n, lA);
      load_lds16(gA0 + k0n + rowstep, lA + 2048);
    }
    __builtin_amdgcn_sched_barrier(0);
    __builtin_amdgcn_s_barrier();
    asm volatile("s_waitcnt lgkmcnt(0)");
    __builtin_amdgcn_sched_barrier(0);
    __builtin_amdgcn_s_setprio(1);
#pragma unroll
    for (int m = 0; m < 4; m++)
#pragma unroll
      for (int n = 0; n < 2; n++)
        acc[m][n] = __builtin_amdgcn_mfma_f32_16x16x32_bf16(af[m], bfr[n], acc[m][n], 0, 0, 0);
    __builtin_amdgcn_s_setprio(0);
    __builtin_amdgcn_sched_barrier(0);
    __builtin_amdgcn_s_barrier();
    bf16x8 bfr2[2];
#pragma unroll
    for (int n = 0; n < 2; n++)
      bfr2[n] = *(const bf16x8*)(Bb + bBase + (n + 2) * 16 * BK);
    if (t + 2 < nk) {
      const int k0n = (t + 2) << 5;
      unsigned short* lB = &Bs[bst][tid * 8];
      load_lds16(gB0 + k0n, lB);
      load_lds16(gB0 + k0n + rowstep, lB + 2048);
    }
    __builtin_amdgcn_sched_barrier(0);
    __builtin_amdgcn_s_barrier();
    asm volatile("s_waitcnt lgkmcnt(0)");
    __builtin_amdgcn_sched_barrier(0);
    __builtin_amdgcn_s_setprio(1);
#pragma unroll
    for (int m = 0; m < 4; m++)
#pragma unroll
      for (int n = 0; n < 2; n++)
        acc[m][n + 2] = __builtin_amdgcn_mfma_f32_16x16x32_bf16(af[m], bfr2[n], acc[m][n + 2], 0, 0, 0);
    __builtin_amdgcn_s_setprio(0);
    __builtin_amdgcn_sched_barrier(0);
    if (t + 1 < nk) {
      if (t + 2 < nk) asm volatile("s_waitcnt vmcnt(4)");
      else asm volatile("s_waitcnt vmcnt(0)");
      __builtin_amdgcn_sched_barrier(0);
    }
    __builtin_amdgcn_s_barrier();
    b = (b == 2) ? 0 : b + 1;
  }
  const int rbase = bm * BM + wr * 64 + (g << 2);
  const int cbase = bn * BN + wc * 64 + frow;
#pragma unroll
  for (int m = 0; m < 4; m++) {
#pragma unroll
    for (int j = 0; j < 4; j++) {
      const int r = rbase + m * 16 + j;
      float* O = (float*)out0;
      size_t ro = (size_t)r * 384;
#pragma unroll
      for (int n = 0; n < 4; n++) {
        int cc = cbase + n * 16;
        O[ro + cc] = acc[m][n][j] + bias[cc] + res[ro + cc];
      }
    }
  }
}

// ---------------- MFMA attention: 4 waves/block, wave-private LDS ----------
// Q/K fragments loaded DIRECTLY from global (row-indexed by lane; rows
// clamped to 48 — duplicates masked by k<49 / qg<49 guards). Only V is
// staged (transposed) + Ps. LDS/wave = 6KB -> 24KB/block -> 6 blocks/CU.
__global__ __launch_bounds__(256) void attn_mfma(const unsigned short* __restrict__ QKV,
                                                 unsigned short* __restrict__ AO) {
  __shared__ __attribute__((aligned(16))) unsigned short L[4][3072];
  const int wid = threadIdx.x >> 6, lane = threadIdx.x & 63;
  const int blk = blockIdx.x * 4 + wid;
  const int win = blk / 12, head = blk - win * 12;
  unsigned short* VT = L[wid];        // [32][64]
  unsigned short* Ps = VT + 2048;     // [16][64]
  const unsigned short* Qp = QKV + (size_t)win * 49 * 1152 + head * 32;
  for (int i = lane; i < 196; i += 64) {
    int row = i >> 2, c8 = (i & 3) << 3;
    s16x8 vv = *(const s16x8*)(Qp + (size_t)row * 1152 + 768 + c8);
#pragma unroll
    for (int u = 0; u < 8; u++) VT[(c8 + u) * 64 + row] = (unsigned short)vv[u];
  }
  for (int i = lane; i < 480; i += 64) {
    int d = i / 15, k = 49 + (i - d * 15);
    VT[d * 64 + k] = 0;
  }

  const int g = lane >> 4, qi = lane & 15;
  const float scale = 0.17677669529663689f;
  bf16x8 kf[4];
#pragma unroll
  for (int mt = 0; mt < 4; mt++) {
    int krow = mt * 16 + qi; if (krow > 48) krow = 48;
    kf[mt] = *(const bf16x8*)(Qp + (size_t)krow * 1152 + 384 + g * 8);
  }

  for (int nt = 0; nt < 4; nt++) {
    int qrow = nt * 16 + qi; if (qrow > 48) qrow = 48;
    bf16x8 qf = *(const bf16x8*)(Qp + (size_t)qrow * 1152 + g * 8);
    f32x4 st[4];
#pragma unroll
    for (int mt = 0; mt < 4; mt++) {
      f32x4 zz = {};
      st[mt] = __builtin_amdgcn_mfma_f32_16x16x32_bf16(kf[mt], qf, zz, 0, 0, 0);
    }
    float m = -1e30f;
#pragma unroll
    for (int mt = 0; mt < 3; mt++)
#pragma unroll
      for (int j = 0; j < 4; j++) m = fmaxf(m, st[mt][j]);
    if (g == 0) m = fmaxf(m, st[3][0]);
    m = fmaxf(m, __shfl_xor(m, 16));
    m = fmaxf(m, __shfl_xor(m, 32));
    m *= scale;
    float p[4][4];
    float sum = 0.f;
#pragma unroll
    for (int mt = 0; mt < 4; mt++)
#pragma unroll
      for (int j = 0; j < 4; j++) {
        int k = mt * 16 + g * 4 + j;
        float e = (k < 49) ? __expf(st[mt][j] * scale - m) : 0.f;
        p[mt][j] = e;
        sum += e;
      }
    sum += __shfl_xor(sum, 16);
    sum += __shfl_xor(sum, 32);
    float inv = 1.0f / sum;
#pragma unroll
    for (int mt = 0; mt < 4; mt++)
#pragma unroll
      for (int j = 0; j < 4; j += 2) {
        unsigned int pk = (unsigned int)f2bf(p[mt][j]) |
                          ((unsigned int)f2bf(p[mt][j + 1]) << 16);
        *(unsigned int*)(Ps + qi * 64 + mt * 16 + g * 4 + j) = pk;
      }
    f32x4 acc0 = {}, acc1 = {};
#pragma unroll
    for (int kt = 0; kt < 2; kt++) {
      bf16x8 pa = *(const bf16x8*)(Ps + qi * 64 + kt * 32 + g * 8);
      bf16x8 vb0 = *(const bf16x8*)(VT + qi * 64 + kt * 32 + g * 8);
      bf16x8 vb1 = *(const bf16x8*)(VT + (16 + qi) * 64 + kt * 32 + g * 8);
      acc0 = __builtin_amdgcn_mfma_f32_16x16x32_bf16(pa, vb0, acc0, 0, 0, 0);
      acc1 = __builtin_amdgcn_mfma_f32_16x16x32_bf16(pa, vb1, acc1, 0, 0, 0);
    }
#pragma unroll
    for (int jr = 0; jr < 4; jr++) {
      int q2 = g * 4 + jr;
      int qg = nt * 16 + q2;
      float iv = __shfl(inv, q2);
      if (qg < 49) {
        unsigned short* op = AO + ((size_t)win * 49 + qg) * 384 + head * 32 + qi;
        op[0] = f2bf(acc0[jr] * iv);
        op[16] = f2bf(acc1[jr] * iv);
      }
    }
  }
}

extern "C" void kernel_launch(void* const* d_in, const int* in_sizes, int n_in,
                              void* d_out, int out_size, void* d_ws, size_t ws_size,
                              hipStream_t stream) {
  (void)in_sizes; (void)n_in; (void)out_size; (void)ws_size;
  const float* x = (const float*)d_in[0];
  const float* g1 = (const float*)d_in[3];
  const float* b1 = (const float*)d_in[4];
  const float* wqkv = (const float*)d_in[5];
  const float* bqkv = (const float*)d_in[6];
  const float* wproj = (const float*)d_in[7];
  const float* bproj = (const float*)d_in[8];
  const float* g2 = (const float*)d_in[9];
  const float* b2 = (const float*)d_in[10];
  const float* wfc1 = (const float*)d_in[11];
  const float* bfc1 = (const float*)d_in[12];
  const float* wfc2 = (const float*)d_in[13];
  const float* bfc2 = (const float*)d_in[14];

  char* ws = (char*)d_ws;
  unsigned short* wtbuf = (unsigned short*)ws;   // all 4 B^T weights, packed
  unsigned short* wqkvT = wtbuf;                 // [1152][384] @ 0
  unsigned short* wprojT = wtbuf + 442368;       // [384][384]
  unsigned short* wfc1T = wtbuf + 589824;        // [1536][384]
  unsigned short* wfc2T = wtbuf + 1179648;       // [384][1536]
  unsigned short* XW = wtbuf + 1769472;          // 100352x384 bf16
  unsigned short* QKV = XW + 38535168;           // 100352x1152 bf16
  unsigned short* AOb = XW;                      // attn out (XW dead)
  unsigned short* XN2 = QKV;                     // LN2 out (QKV dead, 77MB)
  unsigned short* H1buf = QKV + 38535168;        // 50176x1536 bf16
  float* XO = (float*)d_out;                     // residual stream in d_out
  float* out = (float*)d_out;

  wt_all<<<6912, 256, 0, stream>>>(wqkv, wproj, wfc1, wfc2, wtbuf);

  ln_kernel<1><<<25088, 256, 0, stream>>>(x, g1, b1, XW);
  gemmP<0><<<392 * 9, 512, 0, stream>>>(XW, wqkvT, bqkv, 384, 9, QKV, nullptr);
  attn_mfma<<<6144, 256, 0, stream>>>(QKV, AOb);
  gemmP<1><<<392 * 3, 512, 0, stream>>>(AOb, wprojT, bproj, 384, 3, XO, x);
  ln_kernel<0><<<25088, 256, 0, stream>>>(XO, g2, b2, XN2);
  for (int ch = 0; ch < 2; ch++) {
    const unsigned short* a2 = XN2 + (size_t)ch * 50176 * 384;
    float* o2 = out + (size_t)ch * 50176 * 384;
    gemmP<2><<<196 * 12, 512, 0, stream>>>(a2, wfc1T, bfc1, 384, 12, H1buf, nullptr);
    gemmS<3><<<392 * 3, 256, 0, stream>>>(H1buf, wfc2T, bfc2, 1536, 3, o2, o2);
  }
}